// Round 5
// baseline (17109.390 us; speedup 1.0000x reference)
//
#include <hip/hip_runtime.h>

// Zero-workspace fused implementation.
// KEY FIX (R5): the reference computes in jnp.float32 -> the harness passes
// fp32 inputs AND expects an fp32 d_out. (Proven by R2/R3/R4 producing
// bit-identical absmax=2.53125 from three independent implementations: the
// final values were right, only the output encoding was wrong — bf16 pairs
// read back as fp32.) Output dtype now follows the detected input dtype.
// Device math identical to rounds 3/4 (triple-verified).

typedef __bf16 bf16;
typedef float floatx4 __attribute__((ext_vector_type(4)));
typedef __bf16 bf16x8 __attribute__((ext_vector_type(8)));

// bf16 array of N(0,1): even 16-bit words are bf16 values, exponent field
// near 127 -> high hit-rate in [110,140]. fp32 array: even words are low
// mantissa bits (uniform) -> ~12% hit-rate.
__global__ void kt_detect(const unsigned short* x, int* flag) {
  if (threadIdx.x == 0 && blockIdx.x == 0) {
    int cnt = 0;
    for (int i = 0; i < 512; i += 2) {
      const int e = (x[i] >> 7) & 0xFF;
      if (e >= 110 && e <= 140) ++cnt;
    }
    *flag = (cnt >= 128) ? 0 : 1;
  }
}

template <typename T>
__global__ __launch_bounds__(256) void fused(
    const T* __restrict__ pt, const T* __restrict__ x, const T* __restrict__ pp,
    const T* __restrict__ gw0, const T* __restrict__ gb0,
    const T* __restrict__ gw1, const T* __restrict__ gb1,
    const T* __restrict__ gw2, const T* __restrict__ gb2,
    const T* __restrict__ gdw, const T* __restrict__ gdb,
    const T* __restrict__ bw0, const T* __restrict__ bb0,
    const T* __restrict__ bw1, const T* __restrict__ bb1,
    const T* __restrict__ bdw, const T* __restrict__ bdb,
    T* __restrict__ out, const int* __restrict__ flag, int want)
{
  if (*flag != want) return;   // uniform across block; before any barrier

  __shared__ float d0s[1024], d1s[960], d2s[896], red[256], gsh[1], xs[132];
  __shared__ __align__(16) char pool[49152];
  // forward phase layout in pool (15,360 B):
  float* h0s = (float*)pool;           // 1024
  float* h1s = h0s + 1024;             // 960
  float* h2s = h1s + 960;              // 896
  float* e0s = h2s + 896;              // 512
  float* e1s = e0s + 512;              // 448
  // trace phase layout in pool (48,128 B), reuses the same memory:
  float* t0f = (float*)pool;           // [j][g] 1024*8 fp32 = 32,768 B
  bf16*  u1b = (bf16*)(pool + 32768);  // [l][g]  960*8 bf16 = 15,360 B

  const int tid = threadIdx.x;
  const int i = blockIdx.x;

  // xs[0]=s, xs[1..128]=x[i][0..127]
  if (tid < 128) xs[1 + tid] = (float)x[i * 128 + tid];
  if (tid == 128) xs[0] = (float)pt[0];
  __syncthreads();

  // h0 = tanh(xg @ gw0 + gb0), xg = xs[0..127]
  for (int nc = 0; nc < 4; ++nc) {
    const int n = nc * 256 + tid;
    float a = (float)gb0[n];
    for (int j = 0; j < 128; ++j) a += xs[j] * (float)gw0[j * 1024 + n];
    const float t = tanhf(a);
    h0s[n] = t; d0s[n] = 1.0f - t * t;
  }
  __syncthreads();
  // h1 = tanh(h0 @ gw1 + gb1)
  for (int nc = 0; nc < 4; ++nc) {
    const int n = nc * 256 + tid;
    if (n < 960) {
      float a = (float)gb1[n];
      for (int j = 0; j < 1024; ++j) a += h0s[j] * (float)gw1[j * 960 + n];
      const float t = tanhf(a);
      h1s[n] = t; d1s[n] = 1.0f - t * t;
    }
  }
  __syncthreads();
  // h2 = tanh(h1 @ gw2 + gb2)
  for (int nc = 0; nc < 4; ++nc) {
    const int n = nc * 256 + tid;
    if (n < 896) {
      float a = (float)gb2[n];
      for (int j = 0; j < 960; ++j) a += h1s[j] * (float)gw2[j * 896 + n];
      const float t = tanhf(a);
      h2s[n] = t; d2s[n] = 1.0f - t * t;
    }
  }
  __syncthreads();
  // dx_dt = h2 @ gdw + gdb  -> out[0 : 131072]
  if (tid < 128) {
    float a = (float)gdb[tid];
    for (int k = 0; k < 896; ++k) a += h2s[k] * (float)gdw[k * 128 + tid];
    out[i * 128 + tid] = (T)a;
  }
  // e0 = tanh(xb @ bw0 + bb0), xb = xs[0..128] (129 wide)
  for (int nc = 0; nc < 2; ++nc) {
    const int n = nc * 256 + tid;
    float a = (float)bb0[n];
    for (int c = 0; c < 129; ++c) a += xs[c] * (float)bw0[c * 512 + n];
    e0s[n] = tanhf(a);
  }
  __syncthreads();
  // e1 = tanh(e0 @ bw1 + bb1)
  for (int nc = 0; nc < 2; ++nc) {
    const int n = nc * 256 + tid;
    if (n < 448) {
      float a = (float)bb1[n];
      for (int c = 0; c < 512; ++c) a += e0s[c] * (float)bw1[c * 448 + n];
      e1s[n] = tanhf(a);
    }
  }
  __syncthreads();
  // g = e1 . bdw + bdb  -> out[131072 + i]
  float pg = 0.0f;
  for (int c = tid; c < 448; c += 256) pg += e1s[c] * (float)bdw[c];
  red[tid] = pg;
  __syncthreads();
  for (int s = 128; s > 0; s >>= 1) {
    if (tid < s) red[tid] += red[tid + s];
    __syncthreads();
  }
  if (tid == 0) {
    const float g = red[0] + (float)bdb[0];
    gsh[0] = g;
    out[131072 + i] = (T)g;
  }
  __syncthreads();   // forward reads of pool complete; trace may overwrite

  // ---- exact Jacobian trace: 127 tangents in 16 groups of 8 ----
  float ptr = 0.0f;
  for (int grp = 0; grp < 16; ++grp) {
    const int dbase = grp * 8;
    // stage A: t0f[j][g] = d0[j] * gw0[d+1][j]   (d = dbase+g, pad g past 126)
    for (int jc = 0; jc < 4; ++jc) {
      const int j = jc * 256 + tid;
      const float d0v = d0s[j];
      floatx4 lo, hi;
#pragma unroll
      for (int g = 0; g < 4; ++g) {
        const int d = dbase + g;
        lo[g] = (d < 127) ? d0v * (float)gw0[(d + 1) * 1024 + j] : 0.0f;
      }
#pragma unroll
      for (int g = 0; g < 4; ++g) {
        const int d = dbase + 4 + g;
        hi[g] = (d < 127) ? d0v * (float)gw0[(d + 1) * 1024 + j] : 0.0f;
      }
      *(floatx4*)&t0f[j * 8] = lo;
      *(floatx4*)&t0f[j * 8 + 4] = hi;
    }
    __syncthreads();
    // stage B: u1[l][g] = d1[l] * sum_j t0[j][g] * gw1[j][l]
    for (int lc = 0; lc < 4; ++lc) {
      const int l = lc * 256 + tid;
      if (l < 960) {
        float acc[8];
#pragma unroll
        for (int g = 0; g < 8; ++g) acc[g] = 0.0f;
        for (int j = 0; j < 1024; ++j) {
          const float wv = (float)gw1[j * 960 + l];
          const floatx4 lo = *(const floatx4*)&t0f[j * 8];
          const floatx4 hi = *(const floatx4*)&t0f[j * 8 + 4];
#pragma unroll
          for (int g = 0; g < 4; ++g) acc[g] += lo[g] * wv;
#pragma unroll
          for (int g = 0; g < 4; ++g) acc[4 + g] += hi[g] * wv;
        }
        const float d1v = d1s[l];
        bf16x8 uv;
#pragma unroll
        for (int g = 0; g < 8; ++g) uv[g] = (bf16)(d1v * acc[g]);
        *(bf16x8*)&u1b[l * 8] = uv;
      }
    }
    __syncthreads();
    // stage C: ptr += sum_k d2[k]*gdw[k][d] * (sum_l u1[l][g]*gw2[l][k])
    for (int kc = 0; kc < 4; ++kc) {
      const int k = kc * 256 + tid;
      if (k < 896) {
        float acc[8];
#pragma unroll
        for (int g = 0; g < 8; ++g) acc[g] = 0.0f;
        for (int l = 0; l < 960; ++l) {
          const float wv = (float)gw2[l * 896 + k];
          const bf16x8 uv = *(const bf16x8*)&u1b[l * 8];
#pragma unroll
          for (int g = 0; g < 8; ++g) acc[g] += (float)uv[g] * wv;
        }
        const float d2v = d2s[k];
#pragma unroll
        for (int g = 0; g < 8; ++g) {
          const int d = dbase + g;
          if (d < 127) ptr += acc[g] * d2v * (float)gdw[k * 128 + d];
        }
      }
    }
    __syncthreads();
  }
  red[tid] = ptr;
  __syncthreads();
  for (int s = 128; s > 0; s >>= 1) {
    if (tid < s) red[tid] += red[tid + s];
    __syncthreads();
  }
  if (tid == 0)
    out[132096 + i] = (T)(gsh[0] - (float)pp[i] * red[0]);
}

extern "C" void kernel_launch(void* const* d_in, const int* in_sizes, int n_in,
                              void* d_out, int out_size, void* d_ws, size_t ws_size,
                              hipStream_t stream) {
  const void* pt = d_in[0];
  const void* x  = d_in[1];
  const void* pp = d_in[3];
  const void* W[14];
  for (int j = 0; j < 14; ++j) W[j] = d_in[4 + j];
  // W: [gw0, gb0, gw1, gb1, gw2, gb2, gdw, gdb, bw0, bb0, bw1, bb1, bdw, bdb]

  int* flag = (int*)d_ws;                       // only workspace use: 4 bytes

  kt_detect<<<dim3(1), 64, 0, stream>>>((const unsigned short*)x, flag);

  fused<float><<<dim3(1024), 256, 0, stream>>>(
      (const float*)pt, (const float*)x, (const float*)pp,
      (const float*)W[0], (const float*)W[1], (const float*)W[2], (const float*)W[3],
      (const float*)W[4], (const float*)W[5], (const float*)W[6], (const float*)W[7],
      (const float*)W[8], (const float*)W[9], (const float*)W[10], (const float*)W[11],
      (const float*)W[12], (const float*)W[13],
      (float*)d_out, flag, 1);

  fused<bf16><<<dim3(1024), 256, 0, stream>>>(
      (const bf16*)pt, (const bf16*)x, (const bf16*)pp,
      (const bf16*)W[0], (const bf16*)W[1], (const bf16*)W[2], (const bf16*)W[3],
      (const bf16*)W[4], (const bf16*)W[5], (const bf16*)W[6], (const bf16*)W[7],
      (const bf16*)W[8], (const bf16*)W[9], (const bf16*)W[10], (const bf16*)W[11],
      (const bf16*)W[12], (const bf16*)W[13],
      (bf16*)d_out, flag, 0);
}

// Round 6
// 11933.767 us; speedup vs baseline: 1.4337x; 1.4337x over previous
//
#include <hip/hip_runtime.h>

// Hybrid: fp32 fused forward (proven accurate, ~1% of FLOPs) + MFMA bf16
// GEMM pipeline for the Jacobian-trace (99% of FLOPs).
// Facts proven by R0-R5: inputs fp32, output fp32, documented input order,
// ws_size >= ~19 MB, trace math validated by two independent implementations.

typedef __bf16 bf16;
typedef __bf16 bf16x8 __attribute__((ext_vector_type(8)));
typedef float floatx4 __attribute__((ext_vector_type(4)));

#define TILE 64
#define BKC 64
#define LDST 72   // 64 + 8 pad: 16B-aligned, 2-way (free) frag-read conflicts

struct GemmArgs {
  const bf16* A; int lda;
  const bf16* Bt; int ldb;
  int M, N, K;
  // MODE 2 (B1):
  const bf16* gw0b;      // 128x1024 bf16 (rows d+1 used)
  const bf16* d0;        // 1024x1024 bf16
  const bf16* d1;        // 1024x960 bf16
  bf16* Upr;             // out: [n_local][960]
  // MODE 3 (B2):
  const bf16* d2;        // 1024x896 bf16
  const bf16* gdwt;      // 128x896 bf16 (gdwt[d][k] = gdw[k][d])
  float* tr;             // 1024 fp32 accum
  int i0;                // chunk sample base
};

__device__ inline bf16x8 bzero8() {
  bf16x8 v;
#pragma unroll
  for (int i = 0; i < 8; ++i) v[i] = (bf16)0.0f;
  return v;
}

// MODE 2: U' = D1 * (gw1^T @ (D0 * G0-rows)) ; B composed on the fly.
// MODE 3: T = gw2^T @ U' ; epilogue trace-reduce d2*gdwt -> atomicAdd tr[i].
template <int MODE>
__global__ __launch_bounds__(256) void kt_gemm(GemmArgs p) {
  __shared__ bf16 As[TILE * LDST];
  __shared__ bf16 Bs[TILE * LDST];
  const int tid  = threadIdx.x;
  const int m0   = blockIdx.x * TILE;
  const int n0   = blockIdx.y * TILE;
  const int wid  = tid >> 6;
  const int lane = tid & 63;
  const int wm   = wid & 1, wn = wid >> 1;
  const int quad = lane >> 4, l16 = lane & 15;
  const int srow = tid >> 3;          // 0..31
  const int col8 = (tid & 7) << 3;    // 0..56

  floatx4 acc[2][2];
#pragma unroll
  for (int i = 0; i < 2; ++i)
#pragma unroll
    for (int j = 0; j < 2; ++j)
#pragma unroll
      for (int r = 0; r < 4; ++r) acc[i][j][r] = 0.0f;

  for (int kc = 0; kc < p.K; kc += BKC) {
    const int kk = kc + col8;
#pragma unroll
    for (int rr = 0; rr < 2; ++rr) {
      const int r = srow + rr * 32;
      bf16x8 v = *(const bf16x8*)(p.A + (size_t)(m0 + r) * p.lda + kk);
      *(bf16x8*)&As[r * LDST + col8] = v;
    }
#pragma unroll
    for (int rr = 0; rr < 2; ++rr) {
      const int r = srow + rr * 32;
      const int n = n0 + r;
      bf16x8 v;
      if (MODE == 2) {
        const int d = n & 127;
        int wsel = d + 1; if (wsel > 127) wsel = 127;   // d==127 pad col (masked)
        const int ig = p.i0 + (n >> 7);
        bf16x8 gv = *(const bf16x8*)(p.gw0b + wsel * 1024 + kk);
        bf16x8 dv = *(const bf16x8*)(p.d0 + (size_t)ig * 1024 + kk);
#pragma unroll
        for (int j = 0; j < 8; ++j) v[j] = (bf16)((float)gv[j] * (float)dv[j]);
      } else {
        v = *(const bf16x8*)(p.Bt + (size_t)n * p.ldb + kk);
      }
      *(bf16x8*)&Bs[r * LDST + col8] = v;
    }
    __syncthreads();
#pragma unroll
    for (int ks = 0; ks < 2; ++ks) {
      const int kf = ks * 32 + quad * 8;
      bf16x8 af[2], bfv[2];
#pragma unroll
      for (int mt = 0; mt < 2; ++mt)
        af[mt] = *(const bf16x8*)&As[(wm * 32 + mt * 16 + l16) * LDST + kf];
#pragma unroll
      for (int nt = 0; nt < 2; ++nt)
        bfv[nt] = *(const bf16x8*)&Bs[(wn * 32 + nt * 16 + l16) * LDST + kf];
#pragma unroll
      for (int mt = 0; mt < 2; ++mt)
#pragma unroll
        for (int nt = 0; nt < 2; ++nt)
          acc[mt][nt] = __builtin_amdgcn_mfma_f32_16x16x32_bf16(af[mt], bfv[nt], acc[mt][nt], 0, 0, 0);
    }
    __syncthreads();
  }

  if (MODE == 2) {
#pragma unroll
    for (int nt = 0; nt < 2; ++nt) {
      const int ng = n0 + wn * 32 + nt * 16 + l16;          // chunk-local column
      const int ig = p.i0 + (ng >> 7);                       // global sample
#pragma unroll
      for (int mt = 0; mt < 2; ++mt)
#pragma unroll
        for (int r = 0; r < 4; ++r) {
          const int mg = m0 + wm * 32 + mt * 16 + quad * 4 + r;   // j in [0,960)
          const float dd = (float)p.d1[(size_t)ig * 960 + mg];
          p.Upr[(size_t)ng * 960 + mg] = (bf16)(acc[mt][nt][r] * dd);
        }
    }
  } else { // MODE == 3
#pragma unroll
    for (int nt = 0; nt < 2; ++nt) {
      const int ng = n0 + wn * 32 + nt * 16 + l16;
      const int d  = ng & 127;
      const int ig = p.i0 + (ng >> 7);
      float cs = 0.0f;
      if (d < 127) {
#pragma unroll
        for (int mt = 0; mt < 2; ++mt)
#pragma unroll
          for (int r = 0; r < 4; ++r) {
            const int mg = m0 + wm * 32 + mt * 16 + quad * 4 + r;  // k in [0,896)
            const float w = (float)p.d2[(size_t)ig * 896 + mg] * (float)p.gdwt[d * 896 + mg];
            cs += acc[mt][nt][r] * w;
          }
      }
      cs += __shfl_xor(cs, 16, 64);
      cs += __shfl_xor(cs, 32, 64);
      if (quad == 0 && d < 127) atomicAdd(p.tr + ig, cs);
    }
  }
}

// dst (C x ldd) bf16 = transpose(src fp32 (R x C))
__global__ __launch_bounds__(256) void kt_transpose(bf16* dst, const float* src, int R, int C, int ldd) {
  const int idx = blockIdx.x * 256 + threadIdx.x;
  if (idx >= C * ldd) return;
  const int c = idx / ldd, r = idx % ldd;
  dst[idx] = (r < R) ? (bf16)src[(size_t)r * C + c] : (bf16)0.0f;
}

__global__ __launch_bounds__(256) void kt_convert(bf16* dst, const float* src, int n) {
  const int i = blockIdx.x * 256 + threadIdx.x;
  if (i < n) dst[i] = (bf16)src[i];
}

// Forward MLPs (fp32, one block per sample): dx_dt + g outputs, bf16 tanh'
// derivative stores for the trace GEMMs. Trimmed from the R5-passing kernel.
__global__ __launch_bounds__(256) void fwd(
    const float* __restrict__ pt, const float* __restrict__ x,
    const float* __restrict__ gw0, const float* __restrict__ gb0,
    const float* __restrict__ gw1, const float* __restrict__ gb1,
    const float* __restrict__ gw2, const float* __restrict__ gb2,
    const float* __restrict__ gdw, const float* __restrict__ gdb,
    const float* __restrict__ bw0, const float* __restrict__ bb0,
    const float* __restrict__ bw1, const float* __restrict__ bb1,
    const float* __restrict__ bdw, const float* __restrict__ bdb,
    float* __restrict__ out, float* __restrict__ gf,
    bf16* __restrict__ d0b, bf16* __restrict__ d1b, bf16* __restrict__ d2b)
{
  __shared__ float xs[132], h0s[1024], h1s[960], h2s[896], e0s[512], e1s[448], red[256];
  const int tid = threadIdx.x;
  const int i = blockIdx.x;

  if (tid < 128) xs[1 + tid] = x[i * 128 + tid];
  if (tid == 128) xs[0] = pt[0];
  __syncthreads();

  for (int nc = 0; nc < 4; ++nc) {
    const int n = nc * 256 + tid;
    float a = gb0[n];
    for (int j = 0; j < 128; ++j) a += xs[j] * gw0[j * 1024 + n];
    const float t = tanhf(a);
    h0s[n] = t; d0b[(size_t)i * 1024 + n] = (bf16)(1.0f - t * t);
  }
  __syncthreads();
  for (int nc = 0; nc < 4; ++nc) {
    const int n = nc * 256 + tid;
    if (n < 960) {
      float a = gb1[n];
      for (int j = 0; j < 1024; ++j) a += h0s[j] * gw1[j * 960 + n];
      const float t = tanhf(a);
      h1s[n] = t; d1b[(size_t)i * 960 + n] = (bf16)(1.0f - t * t);
    }
  }
  __syncthreads();
  for (int nc = 0; nc < 4; ++nc) {
    const int n = nc * 256 + tid;
    if (n < 896) {
      float a = gb2[n];
      for (int j = 0; j < 960; ++j) a += h1s[j] * gw2[j * 896 + n];
      const float t = tanhf(a);
      h2s[n] = t; d2b[(size_t)i * 896 + n] = (bf16)(1.0f - t * t);
    }
  }
  __syncthreads();
  if (tid < 128) {
    float a = gdb[tid];
    for (int k = 0; k < 896; ++k) a += h2s[k] * gdw[k * 128 + tid];
    out[i * 128 + tid] = a;
  }
  for (int nc = 0; nc < 2; ++nc) {
    const int n = nc * 256 + tid;
    float a = bb0[n];
    for (int c = 0; c < 129; ++c) a += xs[c] * bw0[c * 512 + n];
    e0s[n] = tanhf(a);
  }
  __syncthreads();
  for (int nc = 0; nc < 2; ++nc) {
    const int n = nc * 256 + tid;
    if (n < 448) {
      float a = bb1[n];
      for (int c = 0; c < 512; ++c) a += e0s[c] * bw1[c * 448 + n];
      e1s[n] = tanhf(a);
    }
  }
  __syncthreads();
  float pg = 0.0f;
  for (int c = tid; c < 448; c += 256) pg += e1s[c] * bdw[c];
  red[tid] = pg;
  __syncthreads();
  for (int s = 128; s > 0; s >>= 1) {
    if (tid < s) red[tid] += red[tid + s];
    __syncthreads();
  }
  if (tid == 0) {
    const float g = red[0] + bdb[0];
    gf[i] = g;
    out[131072 + i] = g;
  }
}

__global__ __launch_bounds__(256) void kt_fin(const float* gf, const float* tr,
                                              const float* pp, float* dp) {
  const int i = blockIdx.x * 256 + threadIdx.x;
  if (i < 1024) dp[i] = gf[i] - pp[i] * tr[i];
}

extern "C" void kernel_launch(void* const* d_in, const int* in_sizes, int n_in,
                              void* d_out, int out_size, void* d_ws, size_t ws_size,
                              hipStream_t stream) {
  const float* pt  = (const float*)d_in[0];
  const float* x   = (const float*)d_in[1];
  const float* pp  = (const float*)d_in[3];
  const float* gw0 = (const float*)d_in[4];
  const float* gb0 = (const float*)d_in[5];
  const float* gw1 = (const float*)d_in[6];
  const float* gb1 = (const float*)d_in[7];
  const float* gw2 = (const float*)d_in[8];
  const float* gb2 = (const float*)d_in[9];
  const float* gdw = (const float*)d_in[10];
  const float* gdb = (const float*)d_in[11];
  const float* bw0 = (const float*)d_in[12];
  const float* bb0 = (const float*)d_in[13];
  const float* bw1 = (const float*)d_in[14];
  const float* bb1 = (const float*)d_in[15];
  const float* bdw = (const float*)d_in[16];
  const float* bdb = (const float*)d_in[17];
  float* out = (float*)d_out;

  char* w = (char*)d_ws;
  size_t used = 0;
  auto alloc = [&](size_t nbytes) -> void* {
    void* r = w + used;
    used += (nbytes + 255) & ~(size_t)255;
    return r;
  };
  bf16* gw0b = (bf16*)alloc((size_t)128 * 1024 * 2);
  bf16* gw1t = (bf16*)alloc((size_t)960 * 1024 * 2);
  bf16* gw2t = (bf16*)alloc((size_t)896 * 960 * 2);
  bf16* gdwt = (bf16*)alloc((size_t)128 * 896 * 2);
  bf16* d0b  = (bf16*)alloc((size_t)1024 * 1024 * 2);
  bf16* d1b  = (bf16*)alloc((size_t)1024 * 960 * 2);
  bf16* d2b  = (bf16*)alloc((size_t)1024 * 896 * 2);
  float* gf  = (float*)alloc(1024 * 4);
  float* tr  = (float*)alloc(1024 * 4);
  bf16* Upr  = (bf16*)(w + used);
  const size_t perSample = (size_t)128 * 960 * 2;           // 245,760 B
  size_t avail = (ws_size > used) ? ws_size - used : 0;
  int CH = (int)(avail / perSample);
  if (CH > 1024) CH = 1024;
  if (CH < 1) CH = 1;   // ws >= 19MB proven (R2), so CH >= ~40 in practice

  hipMemsetAsync(tr, 0, 1024 * 4, stream);

  kt_convert<<<dim3(512), 256, 0, stream>>>(gw0b, gw0, 128 * 1024);
  kt_transpose<<<dim3((960 * 1024 + 255) / 256), 256, 0, stream>>>(gw1t, gw1, 1024, 960, 1024);
  kt_transpose<<<dim3((896 * 960 + 255) / 256), 256, 0, stream>>>(gw2t, gw2, 960, 896, 960);
  kt_transpose<<<dim3((128 * 896 + 255) / 256), 256, 0, stream>>>(gdwt, gdw, 896, 128, 896);

  fwd<<<dim3(1024), 256, 0, stream>>>(pt, x, gw0, gb0, gw1, gb1, gw2, gb2,
                                      gdw, gdb, bw0, bb0, bw1, bb1, bdw, bdb,
                                      out, gf, d0b, d1b, d2b);

  for (int i0 = 0; i0 < 1024; i0 += CH) {
    const int ch = (1024 - i0 < CH) ? (1024 - i0) : CH;
    {  // B1: U' = D1 * (gw1^T @ (D0 * G0)),  N = ch*128 tangent-columns
      GemmArgs a{}; a.A = gw1t; a.lda = 1024; a.M = 960; a.N = ch * 128; a.K = 1024;
      a.gw0b = gw0b; a.d0 = d0b; a.d1 = d1b; a.Upr = Upr; a.i0 = i0;
      kt_gemm<2><<<dim3(15, ch * 2), 256, 0, stream>>>(a);
    }
    {  // B2: T = gw2^T @ U', trace-reduce into tr
      GemmArgs a{}; a.A = gw2t; a.lda = 960; a.Bt = Upr; a.ldb = 960;
      a.M = 896; a.N = ch * 128; a.K = 960;
      a.d2 = d2b; a.gdwt = gdwt; a.tr = tr; a.i0 = i0;
      kt_gemm<3><<<dim3(14, ch * 2), 256, 0, stream>>>(a);
    }
  }

  kt_fin<<<dim3(4), 256, 0, stream>>>(gf, tr, pp, out + 132096);
}

// Round 7
// 1466.808 us; speedup vs baseline: 11.6644x; 8.1359x over previous
//
#include <hip/hip_runtime.h>

// R7: m97-structure 128x128x64 MFMA tiles for the Jacobian-trace GEMMs.
// - global_load_lds width-16 staging with XOR-by-row chunk swizzle
//   (DMA-compatible AND conflict-free ds_read_b128 fragment reads)
// - n-tile == one sample (128 tangents): B2 reduces per-block -> 1 atomic/block
// - B1 epilogue: LDS-bounce transpose -> coalesced 16B stores of U'[n][1024]
// - M padded to 1024 (zeroed pad rows; d1-guard) for regular tiles
// Forward MLPs: unchanged fp32 fused kernel (proven R5/R6).

typedef __bf16 bf16;
typedef __bf16 bf16x8 __attribute__((ext_vector_type(8)));
typedef float floatx4 __attribute__((ext_vector_type(4)));

#if defined(__has_builtin)
#if __has_builtin(__builtin_amdgcn_global_load_lds)
#define HAVE_GLL 1
#endif
#endif

typedef __attribute__((address_space(3))) char lds_char_t;
typedef __attribute__((address_space(1))) const char gbl_char_t;

__device__ inline void async_load16(const void* gp, void* lp) {
#ifdef HAVE_GLL
  __builtin_amdgcn_global_load_lds((gbl_char_t*)gp, (lds_char_t*)lp, 16, 0, 0);
#else
  *(bf16x8*)lp = *(const bf16x8*)gp;   // sync fallback, still correct
#endif
}

struct TArgs {
  const bf16* A;        // [Mpad][1024] row-major-k (gw1t padded / gw2t padded)
  const bf16* gw0b;     // B1: [128][1024]
  const bf16* d0b;      // B1: [1024][1024]
  const bf16* d1b;      // B1: [1024][960]
  bf16* Upr;            // B1 out / B2 in: [CH*128][1024]
  const bf16* d2b;      // B2: [1024][896]
  const float* gdw;     // B2: [896][128] fp32 (original layout: lanes coalesce over d)
  float* tr;            // [1024] fp32 accum
  int i0;               // chunk sample base
};

// MODE 0 = B1: U'[n][l] = d1 * (gw1^T @ (d0 * gw0-row)),  one sample per n-tile
// MODE 1 = B2: block-local trace reduce of (gw2^T @ U') with d2*gdw weights
template <int MODE>
__global__ __launch_bounds__(256) void kt_tile(TArgs p) {
  __shared__ __align__(16) char lds[34816];   // max(As+Bs = 32KB, bounce 34.8KB... bounce=128*136*2)
  bf16* As = (bf16*)lds;                      // [128][64] swizzled, 16KB
  bf16* Bs = As + 8192;                       // [128][64] swizzled, 16KB
  bf16* bounce = (bf16*)lds;                  // [128][136] epilogue reuse (B1)
  __shared__ float red4[4];

  const int tid  = threadIdx.x;
  const int wid  = tid >> 6, lane = tid & 63;
  const int wm   = wid & 1, wn = wid >> 1;
  const int quad = lane >> 4, l16 = lane & 15;
  const int sr8  = lane >> 3;                 // 0..7   (async staging row-in-group)
  const int cph  = lane & 7;                  // phys 16B-chunk
  const int br   = tid >> 3;                  // 0..31  (compose staging row)
  const int bc   = tid & 7;
  const int m0   = blockIdx.x * 128;
  const int nb   = blockIdx.y;                // chunk-local sample
  const int ig   = p.i0 + nb;                 // global sample
  const int n0   = nb * 128;                  // Upr row base (chunk-local)

  floatx4 acc[4][4];
#pragma unroll
  for (int a = 0; a < 4; ++a)
#pragma unroll
    for (int b = 0; b < 4; ++b)
#pragma unroll
      for (int r = 0; r < 4; ++r) acc[a][b][r] = 0.0f;

  for (int kc = 0; kc < 1024; kc += 64) {
    // ---- A staging: async DMA, swizzled (LDS[r][c] = glob chunk (c-r)&7) ----
#pragma unroll
    for (int t = 0; t < 4; ++t) {
      const int r = (wid * 4 + t) * 8 + sr8;
      const int csrc = (cph - r) & 7;
      async_load16(p.A + (size_t)(m0 + r) * 1024 + kc + csrc * 8,
                   As + r * 64 + cph * 8);
    }
    // ---- B staging ----
    if (MODE == 0) {
      // compose: Bs[d][j] = gw0b[min(d+1,127)][j] * d0b[ig][j]
#pragma unroll
      for (int rr = 0; rr < 4; ++rr) {
        const int r = br + rr * 32;               // tangent row d
        const int csrc = (bc - r) & 7;
        const int j = kc + csrc * 8;
        const int wsel = (r + 1 < 128) ? (r + 1) : 127;  // d==127 pad col (masked in B2)
        bf16x8 gv = *(const bf16x8*)(p.gw0b + wsel * 1024 + j);
        bf16x8 dv = *(const bf16x8*)(p.d0b + (size_t)ig * 1024 + j);
        bf16x8 v;
#pragma unroll
        for (int e = 0; e < 8; ++e) v[e] = (bf16)((float)gv[e] * (float)dv[e]);
        *(bf16x8*)(Bs + r * 64 + bc * 8) = v;
      }
    } else {
      // async DMA from Upr rows (n-major, [n][1024])
#pragma unroll
      for (int t = 0; t < 4; ++t) {
        const int r = (wid * 4 + t) * 8 + sr8;
        const int csrc = (cph - r) & 7;
        async_load16(p.Upr + (size_t)(n0 + r) * 1024 + kc + csrc * 8,
                     Bs + r * 64 + cph * 8);
      }
    }
    __syncthreads();
    // ---- MFMA: 2 k-steps of 32, 4x4 frags per wave ----
#pragma unroll
    for (int ks = 0; ks < 2; ++ks) {
      bf16x8 af[4], bfv[4];
#pragma unroll
      for (int mt = 0; mt < 4; ++mt) {
        const int r = wm * 64 + mt * 16 + l16;
        const int c = (ks * 4 + quad + r) & 7;
        af[mt] = *(const bf16x8*)(As + r * 64 + c * 8);
      }
#pragma unroll
      for (int nt = 0; nt < 4; ++nt) {
        const int r = wn * 64 + nt * 16 + l16;
        const int c = (ks * 4 + quad + r) & 7;
        bfv[nt] = *(const bf16x8*)(Bs + r * 64 + c * 8);
      }
#pragma unroll
      for (int mt = 0; mt < 4; ++mt)
#pragma unroll
        for (int nt = 0; nt < 4; ++nt)
          acc[mt][nt] = __builtin_amdgcn_mfma_f32_16x16x32_bf16(af[mt], bfv[nt], acc[mt][nt], 0, 0, 0);
    }
    __syncthreads();
  }

  if (MODE == 0) {
    // d1-scale -> bf16 -> LDS bounce (transpose to n-major) -> coalesced store
#pragma unroll
    for (int nt = 0; nt < 4; ++nt) {
      const int nl = wn * 64 + nt * 16 + l16;
#pragma unroll
      for (int mt = 0; mt < 4; ++mt)
#pragma unroll
        for (int r = 0; r < 4; ++r) {
          const int ml = wm * 64 + mt * 16 + quad * 4 + r;
          const int mg = m0 + ml;
          const float d1v = (mg < 960) ? (float)p.d1b[(size_t)ig * 960 + mg] : 0.0f;
          bounce[nl * 136 + ml] = (bf16)(acc[mt][nt][r] * d1v);
        }
    }
    __syncthreads();
    const int r2 = tid >> 1, half = tid & 1;
#pragma unroll
    for (int c = 0; c < 8; ++c) {
      const int ch16 = half * 8 + c;
      bf16x8 v = *(const bf16x8*)(bounce + r2 * 136 + ch16 * 8);
      *(bf16x8*)(p.Upr + (size_t)(n0 + r2) * 1024 + m0 + ch16 * 8) = v;
    }
  } else {
    // block-local trace reduce: one atomic per block
    float s = 0.0f;
#pragma unroll
    for (int nt = 0; nt < 4; ++nt) {
      const int d = wn * 64 + nt * 16 + l16;
      if (d < 127) {
#pragma unroll
        for (int mt = 0; mt < 4; ++mt)
#pragma unroll
          for (int r = 0; r < 4; ++r) {
            const int mg = m0 + wm * 64 + mt * 16 + quad * 4 + r;   // k' in [0,896)
            const float w = (float)p.d2b[(size_t)ig * 896 + mg] * p.gdw[mg * 128 + d];
            s += acc[mt][nt][r] * w;
          }
      }
    }
#pragma unroll
    for (int off = 1; off < 64; off <<= 1) s += __shfl_xor(s, off, 64);
    if (lane == 0) red4[wid] = s;
    __syncthreads();
    if (tid == 0) atomicAdd(p.tr + ig, red4[0] + red4[1] + red4[2] + red4[3]);
  }
}

// dst [dstRows][ldd] bf16; dst[c][r] = src[r][c] (fp32), zero outside (R,C)
__global__ __launch_bounds__(256) void kt_transpose(bf16* dst, const float* src,
                                                    int R, int C, int ldd, int dstRows) {
  const int idx = blockIdx.x * 256 + threadIdx.x;
  if (idx >= dstRows * ldd) return;
  const int c = idx / ldd, r = idx % ldd;
  dst[idx] = (c < C && r < R) ? (bf16)src[(size_t)r * C + c] : (bf16)0.0f;
}

__global__ __launch_bounds__(256) void kt_convert(bf16* dst, const float* src, int n) {
  const int i = blockIdx.x * 256 + threadIdx.x;
  if (i < n) dst[i] = (bf16)src[i];
}

// Forward MLPs (fp32, one block/sample): dx_dt + g outputs, bf16 tanh' stores.
__global__ __launch_bounds__(256) void fwd(
    const float* __restrict__ pt, const float* __restrict__ x,
    const float* __restrict__ gw0, const float* __restrict__ gb0,
    const float* __restrict__ gw1, const float* __restrict__ gb1,
    const float* __restrict__ gw2, const float* __restrict__ gb2,
    const float* __restrict__ gdw, const float* __restrict__ gdb,
    const float* __restrict__ bw0, const float* __restrict__ bb0,
    const float* __restrict__ bw1, const float* __restrict__ bb1,
    const float* __restrict__ bdw, const float* __restrict__ bdb,
    float* __restrict__ out, float* __restrict__ gf,
    bf16* __restrict__ d0b, bf16* __restrict__ d1b, bf16* __restrict__ d2b)
{
  __shared__ float xs[132], h0s[1024], h1s[960], h2s[896], e0s[512], e1s[448], red[256];
  const int tid = threadIdx.x;
  const int i = blockIdx.x;

  if (tid < 128) xs[1 + tid] = x[i * 128 + tid];
  if (tid == 128) xs[0] = pt[0];
  __syncthreads();

  for (int nc = 0; nc < 4; ++nc) {
    const int n = nc * 256 + tid;
    float a = gb0[n];
    for (int j = 0; j < 128; ++j) a += xs[j] * gw0[j * 1024 + n];
    const float t = tanhf(a);
    h0s[n] = t; d0b[(size_t)i * 1024 + n] = (bf16)(1.0f - t * t);
  }
  __syncthreads();
  for (int nc = 0; nc < 4; ++nc) {
    const int n = nc * 256 + tid;
    if (n < 960) {
      float a = gb1[n];
      for (int j = 0; j < 1024; ++j) a += h0s[j] * gw1[j * 960 + n];
      const float t = tanhf(a);
      h1s[n] = t; d1b[(size_t)i * 960 + n] = (bf16)(1.0f - t * t);
    }
  }
  __syncthreads();
  for (int nc = 0; nc < 4; ++nc) {
    const int n = nc * 256 + tid;
    if (n < 896) {
      float a = gb2[n];
      for (int j = 0; j < 960; ++j) a += h1s[j] * gw2[j * 896 + n];
      const float t = tanhf(a);
      h2s[n] = t; d2b[(size_t)i * 896 + n] = (bf16)(1.0f - t * t);
    }
  }
  __syncthreads();
  if (tid < 128) {
    float a = gdb[tid];
    for (int k = 0; k < 896; ++k) a += h2s[k] * gdw[k * 128 + tid];
    out[i * 128 + tid] = a;
  }
  for (int nc = 0; nc < 2; ++nc) {
    const int n = nc * 256 + tid;
    float a = bb0[n];
    for (int c = 0; c < 129; ++c) a += xs[c] * bw0[c * 512 + n];
    e0s[n] = tanhf(a);
  }
  __syncthreads();
  for (int nc = 0; nc < 2; ++nc) {
    const int n = nc * 256 + tid;
    if (n < 448) {
      float a = bb1[n];
      for (int c = 0; c < 512; ++c) a += e0s[c] * bw1[c * 448 + n];
      e1s[n] = tanhf(a);
    }
  }
  __syncthreads();
  float pg = 0.0f;
  for (int c = tid; c < 448; c += 256) pg += e1s[c] * bdw[c];
  red[tid] = pg;
  __syncthreads();
  for (int s = 128; s > 0; s >>= 1) {
    if (tid < s) red[tid] += red[tid + s];
    __syncthreads();
  }
  if (tid == 0) {
    const float g = red[0] + bdb[0];
    gf[i] = g;
    out[131072 + i] = g;
  }
}

__global__ __launch_bounds__(256) void kt_fin(const float* gf, const float* tr,
                                              const float* pp, float* dp) {
  const int i = blockIdx.x * 256 + threadIdx.x;
  if (i < 1024) dp[i] = gf[i] - pp[i] * tr[i];
}

extern "C" void kernel_launch(void* const* d_in, const int* in_sizes, int n_in,
                              void* d_out, int out_size, void* d_ws, size_t ws_size,
                              hipStream_t stream) {
  const float* pt  = (const float*)d_in[0];
  const float* x   = (const float*)d_in[1];
  const float* pp  = (const float*)d_in[3];
  const float* gw0 = (const float*)d_in[4];
  const float* gb0 = (const float*)d_in[5];
  const float* gw1 = (const float*)d_in[6];
  const float* gb1 = (const float*)d_in[7];
  const float* gw2 = (const float*)d_in[8];
  const float* gb2 = (const float*)d_in[9];
  const float* gdw = (const float*)d_in[10];
  const float* gdb = (const float*)d_in[11];
  const float* bw0 = (const float*)d_in[12];
  const float* bb0 = (const float*)d_in[13];
  const float* bw1 = (const float*)d_in[14];
  const float* bb1 = (const float*)d_in[15];
  const float* bdw = (const float*)d_in[16];
  const float* bdb = (const float*)d_in[17];
  float* out = (float*)d_out;

  char* w = (char*)d_ws;
  size_t used = 0;
  auto alloc = [&](size_t nbytes) -> void* {
    void* r = w + used;
    used += (nbytes + 255) & ~(size_t)255;
    return r;
  };
  bf16* gw0b = (bf16*)alloc((size_t)128 * 1024 * 2);
  bf16* gw1t = (bf16*)alloc((size_t)1024 * 1024 * 2);  // [l pad 1024][1024], pad rows zeroed
  bf16* gw2t = (bf16*)alloc((size_t)896 * 1024 * 2);   // [k'][j pad 1024], pad cols zeroed
  bf16* d0b  = (bf16*)alloc((size_t)1024 * 1024 * 2);
  bf16* d1b  = (bf16*)alloc((size_t)1024 * 960 * 2);
  bf16* d2b  = (bf16*)alloc((size_t)1024 * 896 * 2);
  float* gf  = (float*)alloc(1024 * 4);
  float* tr  = (float*)alloc(1024 * 4);
  bf16* Upr  = (bf16*)(w + used);
  const size_t perSample = (size_t)128 * 1024 * 2;     // 262144 B
  size_t avail = (ws_size > used) ? ws_size - used : 0;
  int CH = (int)(avail / perSample);
  if (CH > 1024) CH = 1024;
  if (CH < 1) CH = 1;   // ws >= ~20MB proven (R2) -> CH >= ~37 in practice

  hipMemsetAsync(tr, 0, 1024 * 4, stream);

  kt_convert<<<dim3(512), 256, 0, stream>>>(gw0b, gw0, 128 * 1024);
  kt_transpose<<<dim3((1024 * 1024 + 255) / 256), 256, 0, stream>>>(gw1t, gw1, 1024, 960, 1024, 1024);
  kt_transpose<<<dim3((896 * 1024 + 255) / 256), 256, 0, stream>>>(gw2t, gw2, 960, 896, 1024, 896);

  fwd<<<dim3(1024), 256, 0, stream>>>(pt, x, gw0, gb0, gw1, gb1, gw2, gb2,
                                      gdw, gdb, bw0, bb0, bw1, bb1, bdw, bdb,
                                      out, gf, d0b, d1b, d2b);

  for (int i0 = 0; i0 < 1024; i0 += CH) {
    const int ch = (1024 - i0 < CH) ? (1024 - i0) : CH;
    {  // B1
      TArgs a{}; a.A = gw1t; a.gw0b = gw0b; a.d0b = d0b; a.d1b = d1b;
      a.Upr = Upr; a.i0 = i0;
      kt_tile<0><<<dim3(8, ch), 256, 0, stream>>>(a);
    }
    {  // B2
      TArgs a{}; a.A = gw2t; a.Upr = Upr; a.d2b = d2b; a.gdw = gdw;
      a.tr = tr; a.i0 = i0;
      kt_tile<1><<<dim3(7, ch), 256, 0, stream>>>(a);
    }
  }

  kt_fin<<<dim3(4), 256, 0, stream>>>(gf, tr, pp, out + 132096);
}

// Round 8
// 1179.744 us; speedup vs baseline: 14.5026x; 1.2433x over previous
//
#include <hip/hip_runtime.h>

// R8: all GEMM-shaped work on MFMA.
// - G0 = d0 ⊙ gw0-rows materialized once (kt_g0, HBM-write-bound) -> B1 is a
//   pure dual-async-DMA 128x128x64 tile GEMM (identical structure to B2).
// - Forward MLPs (GRN L0/L1/L2, dx, branch e0/e1) as batched MFMA GEMMs
//   (kt_fwd) with tanh+bias epilogue; d0/d1/d2 stored bf16 as before.
// Proven facts: fp32 in/out, documented input order, ws_size >= ~280 MB.

typedef __bf16 bf16;
typedef __bf16 bf16x8 __attribute__((ext_vector_type(8)));
typedef float floatx4 __attribute__((ext_vector_type(4)));

#if defined(__has_builtin)
#if __has_builtin(__builtin_amdgcn_global_load_lds)
#define HAVE_GLL 1
#endif
#endif

typedef __attribute__((address_space(3))) char lds_char_t;
typedef __attribute__((address_space(1))) const char gbl_char_t;

__device__ inline void async_load16(const void* gp, void* lp) {
#ifdef HAVE_GLL
  __builtin_amdgcn_global_load_lds((gbl_char_t*)gp, (lds_char_t*)lp, 16, 0, 0);
#else
  *(bf16x8*)lp = *(const bf16x8*)gp;   // sync fallback, still correct
#endif
}

// Stage a 128x64 bf16 tile (rows row0..row0+127, cols kc..kc+63 of a [*][ld]
// row-major matrix) into LDS with XOR-by-row chunk swizzle.
__device__ inline void stage_async(const bf16* src, long row0, int ld, int kc,
                                   bf16* dst, int wid, int sr8, int cph) {
#pragma unroll
  for (int t = 0; t < 4; ++t) {
    const int r = (wid * 4 + t) * 8 + sr8;
    const int csrc = (cph - r) & 7;
    async_load16(src + (row0 + r) * (size_t)ld + kc + csrc * 8,
                 dst + r * 64 + cph * 8);
  }
}

__device__ inline void mfma_64(const bf16* As, const bf16* Bs,
                               floatx4 (&acc)[4][4], int wm, int wn,
                               int l16, int quad) {
#pragma unroll
  for (int ks = 0; ks < 2; ++ks) {
    bf16x8 af[4], bfv[4];
#pragma unroll
    for (int mt = 0; mt < 4; ++mt) {
      const int r = wm * 64 + mt * 16 + l16;
      const int c = (ks * 4 + quad + r) & 7;
      af[mt] = *(const bf16x8*)(As + r * 64 + c * 8);
    }
#pragma unroll
    for (int nt = 0; nt < 4; ++nt) {
      const int r = wn * 64 + nt * 16 + l16;
      const int c = (ks * 4 + quad + r) & 7;
      bfv[nt] = *(const bf16x8*)(Bs + r * 64 + c * 8);
    }
#pragma unroll
    for (int mt = 0; mt < 4; ++mt)
#pragma unroll
      for (int nt = 0; nt < 4; ++nt)
        acc[mt][nt] = __builtin_amdgcn_mfma_f32_16x16x32_bf16(af[mt], bfv[nt], acc[mt][nt], 0, 0, 0);
  }
}

// ---------------- trace GEMMs ----------------
struct TArgs {
  const bf16* A;        // [1024][1024] (gw1t / gw2t-pad)
  const bf16* B;        // [ch*128][1024] (G0 for B1, Upr for B2)
  const bf16* d1b;      // B1: [1024][960]
  bf16* Upr;            // B1 out: [ch*128][1024]
  const bf16* d2b;      // B2: [1024][896]
  const float* gdw;     // B2: [896][128] fp32
  float* tr;            // [1024]
  int i0;
};

// MODE 0 = B1: U' rows = d1 * (gw1^T @ G0-rows); MODE 1 = B2: trace reduce.
template <int MODE>
__global__ __launch_bounds__(256) void kt_tile(TArgs p) {
  __shared__ __align__(16) char lds[34816];
  bf16* As = (bf16*)lds;
  bf16* Bs = As + 8192;
  bf16* bounce = (bf16*)lds;    // epilogue reuse (MODE 0), 128*136*2
  __shared__ float red4[4];

  const int tid  = threadIdx.x;
  const int wid  = tid >> 6, lane = tid & 63;
  const int wm   = wid & 1, wn = wid >> 1;
  const int quad = lane >> 4, l16 = lane & 15;
  const int sr8  = lane >> 3, cph = lane & 7;
  const int m0   = blockIdx.x * 128;
  const int nb   = blockIdx.y;
  const int ig   = p.i0 + nb;
  const int n0   = nb * 128;

  floatx4 acc[4][4];
#pragma unroll
  for (int a = 0; a < 4; ++a)
#pragma unroll
    for (int b = 0; b < 4; ++b)
#pragma unroll
      for (int r = 0; r < 4; ++r) acc[a][b][r] = 0.0f;

  for (int kc = 0; kc < 1024; kc += 64) {
    stage_async(p.A, m0, 1024, kc, As, wid, sr8, cph);
    stage_async(p.B, n0, 1024, kc, Bs, wid, sr8, cph);
    __syncthreads();
    mfma_64(As, Bs, acc, wm, wn, l16, quad);
    __syncthreads();
  }

  if (MODE == 0) {
#pragma unroll
    for (int nt = 0; nt < 4; ++nt) {
      const int nl = wn * 64 + nt * 16 + l16;
#pragma unroll
      for (int mt = 0; mt < 4; ++mt)
#pragma unroll
        for (int r = 0; r < 4; ++r) {
          const int ml = wm * 64 + mt * 16 + quad * 4 + r;
          const int mg = m0 + ml;
          const float d1v = (mg < 960) ? (float)p.d1b[(size_t)ig * 960 + mg] : 0.0f;
          bounce[nl * 136 + ml] = (bf16)(acc[mt][nt][r] * d1v);
        }
    }
    __syncthreads();
    const int r2 = tid >> 1, half = tid & 1;
#pragma unroll
    for (int c = 0; c < 8; ++c) {
      const int ch16 = half * 8 + c;
      bf16x8 v = *(const bf16x8*)(bounce + r2 * 136 + ch16 * 8);
      *(bf16x8*)(p.Upr + (size_t)(n0 + r2) * 1024 + m0 + ch16 * 8) = v;
    }
  } else {
    float s = 0.0f;
#pragma unroll
    for (int nt = 0; nt < 4; ++nt) {
      const int d = wn * 64 + nt * 16 + l16;
      if (d < 127) {
#pragma unroll
        for (int mt = 0; mt < 4; ++mt)
#pragma unroll
          for (int r = 0; r < 4; ++r) {
            const int mg = m0 + wm * 64 + mt * 16 + quad * 4 + r;   // k' in [0,896)
            const float w = (float)p.d2b[(size_t)ig * 896 + mg] * p.gdw[mg * 128 + d];
            s += acc[mt][nt][r] * w;
          }
      }
    }
#pragma unroll
    for (int off = 1; off < 64; off <<= 1) s += __shfl_xor(s, off, 64);
    if (lane == 0) red4[wid] = s;
    __syncthreads();
    if (tid == 0) atomicAdd(p.tr + ig, red4[0] + red4[1] + red4[2] + red4[3]);
  }
}

// ---------------- forward GEMMs ----------------
struct FArgs {
  const bf16* A; int lda;    // [1024][lda] activations (i-major)
  const bf16* Bt; int ldb;   // [Npad][ldb] transposed weights (n-major)
  const float* bias;
  bf16* C; int ldc;          // ACT=1: bf16 h store (pad cols -> 0)
  bf16* D; int ldd;          // optional 1-t^2 store
  float* outF; int ldo;      // ACT=0: fp32 store
  int K; int realN;
};

template <int ACT>
__global__ __launch_bounds__(256) void kt_fwd(FArgs p) {
  __shared__ __align__(16) bf16 As[8192];
  __shared__ __align__(16) bf16 Bs[8192];
  const int tid  = threadIdx.x;
  const int wid  = tid >> 6, lane = tid & 63;
  const int wm   = wid & 1, wn = wid >> 1;
  const int quad = lane >> 4, l16 = lane & 15;
  const int sr8  = lane >> 3, cph = lane & 7;
  const int m0   = blockIdx.x * 128;     // sample tile
  const int bn0  = blockIdx.y * 128;     // unit tile

  floatx4 acc[4][4];
#pragma unroll
  for (int a = 0; a < 4; ++a)
#pragma unroll
    for (int b = 0; b < 4; ++b)
#pragma unroll
      for (int r = 0; r < 4; ++r) acc[a][b][r] = 0.0f;

  for (int kc = 0; kc < p.K; kc += 64) {
    stage_async(p.A, m0, p.lda, kc, As, wid, sr8, cph);
    stage_async(p.Bt, bn0, p.ldb, kc, Bs, wid, sr8, cph);
    __syncthreads();
    mfma_64(As, Bs, acc, wm, wn, l16, quad);
    __syncthreads();
  }

#pragma unroll
  for (int nt = 0; nt < 4; ++nt) {
    const int ng = bn0 + wn * 64 + nt * 16 + l16;
    const float bv = (ng < p.realN) ? p.bias[ng] : 0.0f;
#pragma unroll
    for (int mt = 0; mt < 4; ++mt)
#pragma unroll
      for (int r = 0; r < 4; ++r) {
        const int i = m0 + wm * 64 + mt * 16 + quad * 4 + r;
        const float v = acc[mt][nt][r] + bv;
        if (ACT) {
          const float t = tanhf(v);
          p.C[(size_t)i * p.ldc + ng] = (ng < p.realN) ? (bf16)t : (bf16)0.0f;
          if (p.D && ng < p.realN)
            p.D[(size_t)i * p.ldd + ng] = (bf16)(1.0f - t * t);
        } else if (ng < p.realN) {
          p.outF[(size_t)i * p.ldo + ng] = v;
        }
      }
  }
}

// ---------------- small helpers ----------------
// dst [dstRows][ldd] bf16; dst[c][r] = src[r][c] (fp32), zero outside (R,C)
__global__ __launch_bounds__(256) void kt_transpose(bf16* dst, const float* src,
                                                    int R, int C, int ldd, int dstRows) {
  const int idx = blockIdx.x * 256 + threadIdx.x;
  if (idx >= dstRows * ldd) return;
  const int c = idx / ldd, r = idx % ldd;
  dst[idx] = (c < C && r < R) ? (bf16)src[(size_t)r * C + c] : (bf16)0.0f;
}

__global__ __launch_bounds__(256) void kt_convert(bf16* dst, const float* src, int n) {
  const int i = blockIdx.x * 256 + threadIdx.x;
  if (i < n) dst[i] = (bf16)src[i];
}

// Xg [1024][128]: [s, x[0..126]]; Xb [1024][192]: [s, x[0..127], 0...]
__global__ __launch_bounds__(256) void kt_build(const float* pt, const float* x,
                                                bf16* Xg, bf16* Xb) {
  const int idx = blockIdx.x * 256 + threadIdx.x;
  if (idx >= 1024 * 192) return;
  const int i = idx / 192, c = idx % 192;
  const float s = pt[0];
  float vb;
  if (c == 0) vb = s;
  else if (c <= 128) vb = x[i * 128 + c - 1];
  else vb = 0.0f;
  Xb[i * 192 + c] = (bf16)vb;
  if (c < 128) Xg[i * 128 + c] = (bf16)((c == 0) ? s : x[i * 128 + c - 1]);
}

// G0[n][j] = d0b[ig][j] * gw0b[min(d+1,127)][j], n = local_sample*128 + d
__global__ __launch_bounds__(256) void kt_g0(bf16* G0, const bf16* gw0b,
                                             const bf16* d0b, int i0, int ch) {
  const int idx = blockIdx.x * 256 + threadIdx.x;
  if (idx >= ch * 16384) return;
  const int n = idx >> 7, j = (idx & 127) << 3;
  const int d = n & 127;
  const int ig = i0 + (n >> 7);
  const int wsel = (d + 1 < 128) ? d + 1 : 127;   // d==127 pad col (masked in B2)
  bf16x8 gv = *(const bf16x8*)(gw0b + wsel * 1024 + j);
  bf16x8 dv = *(const bf16x8*)(d0b + (size_t)ig * 1024 + j);
  bf16x8 v;
#pragma unroll
  for (int e = 0; e < 8; ++e) v[e] = (bf16)((float)gv[e] * (float)dv[e]);
  *(bf16x8*)(G0 + (size_t)n * 1024 + j) = v;
}

// g[i] = e1[i,:448] . bdw + bdb  (one wave per sample; e1 bf16 ld 512)
__global__ __launch_bounds__(256) void kt_gdot(const bf16* e1b, const float* bdw,
                                               const float* bdb, float* gf, float* gout) {
  const int i = blockIdx.x * 4 + (threadIdx.x >> 6);
  const int lane = threadIdx.x & 63;
  float s = 0.0f;
  for (int k = lane; k < 448; k += 64) s += (float)e1b[(size_t)i * 512 + k] * bdw[k];
#pragma unroll
  for (int off = 32; off > 0; off >>= 1) s += __shfl_down(s, off, 64);
  if (lane == 0) {
    const float v = s + bdb[0];
    gf[i] = v;
    gout[i] = v;
  }
}

__global__ __launch_bounds__(256) void kt_fin(const float* gf, const float* tr,
                                              const float* pp, float* dp) {
  const int i = blockIdx.x * 256 + threadIdx.x;
  if (i < 1024) dp[i] = gf[i] - pp[i] * tr[i];
}

extern "C" void kernel_launch(void* const* d_in, const int* in_sizes, int n_in,
                              void* d_out, int out_size, void* d_ws, size_t ws_size,
                              hipStream_t stream) {
  const float* pt  = (const float*)d_in[0];
  const float* x   = (const float*)d_in[1];
  const float* pp  = (const float*)d_in[3];
  const float* gw0 = (const float*)d_in[4];
  const float* gb0 = (const float*)d_in[5];
  const float* gw1 = (const float*)d_in[6];
  const float* gb1 = (const float*)d_in[7];
  const float* gw2 = (const float*)d_in[8];
  const float* gb2 = (const float*)d_in[9];
  const float* gdw = (const float*)d_in[10];
  const float* gdb = (const float*)d_in[11];
  const float* bw0 = (const float*)d_in[12];
  const float* bb0 = (const float*)d_in[13];
  const float* bw1 = (const float*)d_in[14];
  const float* bb1 = (const float*)d_in[15];
  const float* bdw = (const float*)d_in[16];
  const float* bdb = (const float*)d_in[17];
  float* out = (float*)d_out;

  char* w = (char*)d_ws;
  size_t used = 0;
  auto alloc = [&](size_t nbytes) -> void* {
    void* r = w + used;
    used += (nbytes + 255) & ~(size_t)255;
    return r;
  };
  bf16* gw0b = (bf16*)alloc((size_t)128 * 1024 * 2);   // gw0 bf16 copy
  bf16* gw0t = (bf16*)alloc((size_t)1024 * 128 * 2);   // [n][j=128]
  bf16* gw1t = (bf16*)alloc((size_t)1024 * 1024 * 2);  // [n pad][j] (also B1 A)
  bf16* gw2t = (bf16*)alloc((size_t)896 * 1024 * 2);   // [k'][l pad] (also B2 A)
  bf16* gdwt = (bf16*)alloc((size_t)128 * 1024 * 2);   // [gene][k' pad]
  bf16* bw0t = (bf16*)alloc((size_t)512 * 192 * 2);
  bf16* bw1t = (bf16*)alloc((size_t)512 * 512 * 2);    // rows >=448 zero
  bf16* Xg   = (bf16*)alloc((size_t)1024 * 128 * 2);
  bf16* Xb   = (bf16*)alloc((size_t)1024 * 192 * 2);
  bf16* h0b  = (bf16*)alloc((size_t)1024 * 1024 * 2);
  bf16* h1b  = (bf16*)alloc((size_t)1024 * 1024 * 2);  // pad cols zeroed
  bf16* h2b  = (bf16*)alloc((size_t)1024 * 1024 * 2);
  bf16* e0b  = (bf16*)alloc((size_t)1024 * 512 * 2);
  bf16* e1b  = (bf16*)alloc((size_t)1024 * 512 * 2);   // pad cols zeroed
  bf16* d0b  = (bf16*)alloc((size_t)1024 * 1024 * 2);
  bf16* d1b  = (bf16*)alloc((size_t)1024 * 960 * 2);
  bf16* d2b  = (bf16*)alloc((size_t)1024 * 896 * 2);
  float* gf  = (float*)alloc(1024 * 4);
  float* tr  = (float*)alloc(1024 * 4);

  const size_t perSample = (size_t)128 * 1024 * 2;     // 256 KB
  size_t avail = (ws_size > used) ? ws_size - used : 0;
  int CH = (int)(avail / (2 * perSample));             // G0 + Upr per sample
  if (CH > 1024) CH = 1024;
  if (CH < 1) CH = 1;                                  // ws >= ~280MB proven -> CH >= ~490
  bf16* G0  = (bf16*)alloc((size_t)CH * perSample);
  bf16* Upr = (bf16*)(w + used);

  hipMemsetAsync(tr, 0, 1024 * 4, stream);

  // weight prep + input build
  kt_convert<<<dim3(512), 256, 0, stream>>>(gw0b, gw0, 128 * 1024);
  kt_transpose<<<dim3(512), 256, 0, stream>>>(gw0t, gw0, 128, 1024, 128, 1024);
  kt_transpose<<<dim3(4096), 256, 0, stream>>>(gw1t, gw1, 1024, 960, 1024, 1024);
  kt_transpose<<<dim3(3584), 256, 0, stream>>>(gw2t, gw2, 960, 896, 1024, 896);
  kt_transpose<<<dim3(512), 256, 0, stream>>>(gdwt, gdw, 896, 128, 1024, 128);
  kt_transpose<<<dim3(384), 256, 0, stream>>>(bw0t, bw0, 129, 512, 192, 512);
  kt_transpose<<<dim3(1024), 256, 0, stream>>>(bw1t, bw1, 512, 448, 512, 512);
  kt_build<<<dim3(768), 256, 0, stream>>>(pt, x, Xg, Xb);

  // forward GEMMs
  {  // L0: h0 = tanh(Xg @ gw0 + gb0), d0
    FArgs a{}; a.A = Xg; a.lda = 128; a.Bt = gw0t; a.ldb = 128; a.bias = gb0;
    a.C = h0b; a.ldc = 1024; a.D = d0b; a.ldd = 1024; a.K = 128; a.realN = 1024;
    kt_fwd<1><<<dim3(8, 8), 256, 0, stream>>>(a);
  }
  {  // L1: h1 = tanh(h0 @ gw1 + gb1), d1
    FArgs a{}; a.A = h0b; a.lda = 1024; a.Bt = gw1t; a.ldb = 1024; a.bias = gb1;
    a.C = h1b; a.ldc = 1024; a.D = d1b; a.ldd = 960; a.K = 1024; a.realN = 960;
    kt_fwd<1><<<dim3(8, 8), 256, 0, stream>>>(a);
  }
  {  // L2: h2 = tanh(h1 @ gw2 + gb2), d2
    FArgs a{}; a.A = h1b; a.lda = 1024; a.Bt = gw2t; a.ldb = 1024; a.bias = gb2;
    a.C = h2b; a.ldc = 1024; a.D = d2b; a.ldd = 896; a.K = 1024; a.realN = 896;
    kt_fwd<1><<<dim3(8, 7), 256, 0, stream>>>(a);
  }
  {  // dx_dt = h2 @ gdw + gdb -> out (fp32), K=896 (14x64, no pad read)
    FArgs a{}; a.A = h2b; a.lda = 1024; a.Bt = gdwt; a.ldb = 1024; a.bias = gdb;
    a.outF = out; a.ldo = 128; a.K = 896; a.realN = 128;
    kt_fwd<0><<<dim3(8, 1), 256, 0, stream>>>(a);
  }
  {  // e0 = tanh(Xb @ bw0 + bb0), K=192 (129 padded)
    FArgs a{}; a.A = Xb; a.lda = 192; a.Bt = bw0t; a.ldb = 192; a.bias = bb0;
    a.C = e0b; a.ldc = 512; a.K = 192; a.realN = 512;
    kt_fwd<1><<<dim3(8, 4), 256, 0, stream>>>(a);
  }
  {  // e1 = tanh(e0 @ bw1 + bb1), N=448 padded 512
    FArgs a{}; a.A = e0b; a.lda = 512; a.Bt = bw1t; a.ldb = 512; a.bias = bb1;
    a.C = e1b; a.ldc = 512; a.K = 512; a.realN = 448;
    kt_fwd<1><<<dim3(8, 4), 256, 0, stream>>>(a);
  }
  kt_gdot<<<dim3(256), 256, 0, stream>>>(e1b, bdw, bdb, gf, out + 131072);

  // trace GEMMs, chunked over samples
  for (int i0 = 0; i0 < 1024; i0 += CH) {
    const int ch = (1024 - i0 < CH) ? (1024 - i0) : CH;
    kt_g0<<<dim3((ch * 16384 + 255) / 256), 256, 0, stream>>>(G0, gw0b, d0b, i0, ch);
    {  // B1: U' = D1 * (gw1^T @ G0)
      TArgs a{}; a.A = gw1t; a.B = G0; a.d1b = d1b; a.Upr = Upr; a.i0 = i0;
      kt_tile<0><<<dim3(8, ch), 256, 0, stream>>>(a);
    }
    {  // B2: trace reduce of gw2^T @ U'
      TArgs a{}; a.A = gw2t; a.B = Upr; a.d2b = d2b; a.gdw = gdw; a.tr = tr; a.i0 = i0;
      kt_tile<1><<<dim3(7, ch), 256, 0, stream>>>(a);
    }
  }

  kt_fin<<<dim3(4), 256, 0, stream>>>(gf, tr, pp, out + 132096);
}

// Round 9
// 1141.693 us; speedup vs baseline: 14.9860x; 1.0333x over previous
//
#include <hip/hip_runtime.h>

// R9: traffic-optimized trace GEMMs.
// - kt_tile m-tile 256 (4 waves over m, acc 4x8): B-side re-reads halved,
//   2x MFMA per staged byte. MODE-0 epilogue in two half-m bounce passes.
// - CH capped at 256 so per-chunk G0+Upr (~134 MB) stays L3-resident:
//   the 4x m-tile re-reads hit L3, HBM carries only write-backs.
// Proven: fp32 in/out, documented input order, ws >= ~280 MB, CH arithmetic.

typedef __bf16 bf16;
typedef __bf16 bf16x8 __attribute__((ext_vector_type(8)));
typedef float floatx4 __attribute__((ext_vector_type(4)));

#if defined(__has_builtin)
#if __has_builtin(__builtin_amdgcn_global_load_lds)
#define HAVE_GLL 1
#endif
#endif

typedef __attribute__((address_space(3))) char lds_char_t;
typedef __attribute__((address_space(1))) const char gbl_char_t;

__device__ inline void async_load16(const void* gp, void* lp) {
#ifdef HAVE_GLL
  __builtin_amdgcn_global_load_lds((gbl_char_t*)gp, (lds_char_t*)lp, 16, 0, 0);
#else
  *(bf16x8*)lp = *(const bf16x8*)gp;   // sync fallback, still correct
#endif
}

// Stage a 128x64 bf16 tile into LDS with XOR-by-row chunk swizzle.
__device__ inline void stage_async(const bf16* src, long row0, int ld, int kc,
                                   bf16* dst, int wid, int sr8, int cph) {
#pragma unroll
  for (int t = 0; t < 4; ++t) {
    const int r = (wid * 4 + t) * 8 + sr8;
    const int csrc = (cph - r) & 7;
    async_load16(src + (row0 + r) * (size_t)ld + kc + csrc * 8,
                 dst + r * 64 + cph * 8);
  }
}

// ---------------- trace GEMMs (m-tile 256) ----------------
struct TArgs {
  const bf16* A;        // [1024][1024] (gw1t / gw2t, zero-padded)
  const bf16* B;        // [ch*128][1024] (G0 for B1, Upr for B2)
  const bf16* d1b;      // B1: [1024][960]
  bf16* Upr;            // B1 out: [ch*128][1024]
  const bf16* d2b;      // B2: [1024][896]
  const float* gdw;     // B2: [896][128] fp32
  float* tr;            // [1024]
  int i0;
};

// MODE 0 = B1: U' rows = d1 * (gw1^T @ G0-rows); MODE 1 = B2: trace reduce.
template <int MODE>
__global__ __launch_bounds__(256, 2) void kt_tile(TArgs p) {
  __shared__ __align__(16) char lds[49152];   // As 32KB + Bs 16KB; bounce reuse
  bf16* As = (bf16*)lds;            // [256][64] swizzled
  bf16* Bs = As + 16384;            // [128][64] swizzled
  bf16* bounce = (bf16*)lds;        // [128][136] epilogue reuse (MODE 0)
  __shared__ float red4[4];

  const int tid  = threadIdx.x;
  const int wid  = tid >> 6, lane = tid & 63;   // wave wid owns m-rows [wid*64, wid*64+64)
  const int quad = lane >> 4, l16 = lane & 15;
  const int sr8  = lane >> 3, cph = lane & 7;
  const int m0   = blockIdx.x * 256;
  const int nb   = blockIdx.y;
  const int ig   = p.i0 + nb;
  const int n0   = nb * 128;

  floatx4 acc[4][8];
#pragma unroll
  for (int a = 0; a < 4; ++a)
#pragma unroll
    for (int b = 0; b < 8; ++b)
#pragma unroll
      for (int r = 0; r < 4; ++r) acc[a][b][r] = 0.0f;

  for (int kc = 0; kc < 1024; kc += 64) {
    // A: 256 rows (8 DMA/thread)
#pragma unroll
    for (int t = 0; t < 8; ++t) {
      const int r = (wid * 8 + t) * 8 + sr8;
      const int csrc = (cph - r) & 7;
      async_load16(p.A + (size_t)(m0 + r) * 1024 + kc + csrc * 8,
                   As + r * 64 + cph * 8);
    }
    // B: 128 rows (4 DMA/thread)
    stage_async(p.B, n0, 1024, kc, Bs, wid, sr8, cph);
    __syncthreads();
#pragma unroll
    for (int ks = 0; ks < 2; ++ks) {
      bf16x8 af[4], bfv[8];
#pragma unroll
      for (int mt = 0; mt < 4; ++mt) {
        const int r = wid * 64 + mt * 16 + l16;
        const int c = (ks * 4 + quad + r) & 7;
        af[mt] = *(const bf16x8*)(As + r * 64 + c * 8);
      }
#pragma unroll
      for (int nt = 0; nt < 8; ++nt) {
        const int r = nt * 16 + l16;
        const int c = (ks * 4 + quad + r) & 7;
        bfv[nt] = *(const bf16x8*)(Bs + r * 64 + c * 8);
      }
#pragma unroll
      for (int mt = 0; mt < 4; ++mt)
#pragma unroll
        for (int nt = 0; nt < 8; ++nt)
          acc[mt][nt] = __builtin_amdgcn_mfma_f32_16x16x32_bf16(af[mt], bfv[nt], acc[mt][nt], 0, 0, 0);
    }
    __syncthreads();
  }

  if (MODE == 0) {
    // two half-m passes: d1-scale -> bf16 bounce transpose -> coalesced store
    for (int h = 0; h < 2; ++h) {
      __syncthreads();
      if ((wid >> 1) == h) {
        const int wbase = (wid & 1) * 64;
#pragma unroll
        for (int nt = 0; nt < 8; ++nt) {
          const int nl = nt * 16 + l16;
#pragma unroll
          for (int mt = 0; mt < 4; ++mt)
#pragma unroll
            for (int r = 0; r < 4; ++r) {
              const int ml = wbase + mt * 16 + quad * 4 + r;    // 0..127 in half
              const int mg = m0 + h * 128 + ml;
              const float d1v = (mg < 960) ? (float)p.d1b[(size_t)ig * 960 + mg] : 0.0f;
              bounce[nl * 136 + ml] = (bf16)(acc[mt][nt][r] * d1v);
            }
        }
      }
      __syncthreads();
      const int r2 = tid >> 1, half16 = tid & 1;
#pragma unroll
      for (int c = 0; c < 8; ++c) {
        const int ch16 = half16 * 8 + c;
        bf16x8 v = *(const bf16x8*)(bounce + r2 * 136 + ch16 * 8);
        *(bf16x8*)(p.Upr + (size_t)(n0 + r2) * 1024 + m0 + h * 128 + ch16 * 8) = v;
      }
    }
  } else {
    float s = 0.0f;
#pragma unroll
    for (int nt = 0; nt < 8; ++nt) {
      const int d = nt * 16 + l16;
      if (d < 127) {
#pragma unroll
        for (int mt = 0; mt < 4; ++mt)
#pragma unroll
          for (int r = 0; r < 4; ++r) {
            const int mg = m0 + wid * 64 + mt * 16 + quad * 4 + r;  // k' in [0,1024)
            if (mg < 896) {
              const float w = (float)p.d2b[(size_t)ig * 896 + mg] * p.gdw[mg * 128 + d];
              s += acc[mt][nt][r] * w;
            }
          }
      }
    }
#pragma unroll
    for (int off = 1; off < 64; off <<= 1) s += __shfl_xor(s, off, 64);
    if (lane == 0) red4[wid] = s;
    __syncthreads();
    if (tid == 0) atomicAdd(p.tr + ig, red4[0] + red4[1] + red4[2] + red4[3]);
  }
}

// ---------------- forward GEMMs (unchanged from R8) ----------------
struct FArgs {
  const bf16* A; int lda;
  const bf16* Bt; int ldb;
  const float* bias;
  bf16* C; int ldc;
  bf16* D; int ldd;
  float* outF; int ldo;
  int K; int realN;
};

template <int ACT>
__global__ __launch_bounds__(256) void kt_fwd(FArgs p) {
  __shared__ __align__(16) bf16 As[8192];
  __shared__ __align__(16) bf16 Bs[8192];
  const int tid  = threadIdx.x;
  const int wid  = tid >> 6, lane = tid & 63;
  const int wm   = wid & 1, wn = wid >> 1;
  const int quad = lane >> 4, l16 = lane & 15;
  const int sr8  = lane >> 3, cph = lane & 7;
  const int m0   = blockIdx.x * 128;
  const int bn0  = blockIdx.y * 128;

  floatx4 acc[4][4];
#pragma unroll
  for (int a = 0; a < 4; ++a)
#pragma unroll
    for (int b = 0; b < 4; ++b)
#pragma unroll
      for (int r = 0; r < 4; ++r) acc[a][b][r] = 0.0f;

  for (int kc = 0; kc < p.K; kc += 64) {
    stage_async(p.A, m0, p.lda, kc, As, wid, sr8, cph);
    stage_async(p.Bt, bn0, p.ldb, kc, Bs, wid, sr8, cph);
    __syncthreads();
#pragma unroll
    for (int ks = 0; ks < 2; ++ks) {
      bf16x8 af[4], bfv[4];
#pragma unroll
      for (int mt = 0; mt < 4; ++mt) {
        const int r = wm * 64 + mt * 16 + l16;
        const int c = (ks * 4 + quad + r) & 7;
        af[mt] = *(const bf16x8*)(As + r * 64 + c * 8);
      }
#pragma unroll
      for (int nt = 0; nt < 4; ++nt) {
        const int r = wn * 64 + nt * 16 + l16;
        const int c = (ks * 4 + quad + r) & 7;
        bfv[nt] = *(const bf16x8*)(Bs + r * 64 + c * 8);
      }
#pragma unroll
      for (int mt = 0; mt < 4; ++mt)
#pragma unroll
        for (int nt = 0; nt < 4; ++nt)
          acc[mt][nt] = __builtin_amdgcn_mfma_f32_16x16x32_bf16(af[mt], bfv[nt], acc[mt][nt], 0, 0, 0);
    }
    __syncthreads();
  }

#pragma unroll
  for (int nt = 0; nt < 4; ++nt) {
    const int ng = bn0 + wn * 64 + nt * 16 + l16;
    const float bv = (ng < p.realN) ? p.bias[ng] : 0.0f;
#pragma unroll
    for (int mt = 0; mt < 4; ++mt)
#pragma unroll
      for (int r = 0; r < 4; ++r) {
        const int i = m0 + wm * 64 + mt * 16 + quad * 4 + r;
        const float v = acc[mt][nt][r] + bv;
        if (ACT) {
          const float t = tanhf(v);
          p.C[(size_t)i * p.ldc + ng] = (ng < p.realN) ? (bf16)t : (bf16)0.0f;
          if (p.D && ng < p.realN)
            p.D[(size_t)i * p.ldd + ng] = (bf16)(1.0f - t * t);
        } else if (ng < p.realN) {
          p.outF[(size_t)i * p.ldo + ng] = v;
        }
      }
  }
}

// ---------------- small helpers ----------------
__global__ __launch_bounds__(256) void kt_transpose(bf16* dst, const float* src,
                                                    int R, int C, int ldd, int dstRows) {
  const int idx = blockIdx.x * 256 + threadIdx.x;
  if (idx >= dstRows * ldd) return;
  const int c = idx / ldd, r = idx % ldd;
  dst[idx] = (c < C && r < R) ? (bf16)src[(size_t)r * C + c] : (bf16)0.0f;
}

__global__ __launch_bounds__(256) void kt_convert(bf16* dst, const float* src, int n) {
  const int i = blockIdx.x * 256 + threadIdx.x;
  if (i < n) dst[i] = (bf16)src[i];
}

__global__ __launch_bounds__(256) void kt_build(const float* pt, const float* x,
                                                bf16* Xg, bf16* Xb) {
  const int idx = blockIdx.x * 256 + threadIdx.x;
  if (idx >= 1024 * 192) return;
  const int i = idx / 192, c = idx % 192;
  const float s = pt[0];
  float vb;
  if (c == 0) vb = s;
  else if (c <= 128) vb = x[i * 128 + c - 1];
  else vb = 0.0f;
  Xb[i * 192 + c] = (bf16)vb;
  if (c < 128) Xg[i * 128 + c] = (bf16)((c == 0) ? s : x[i * 128 + c - 1]);
}

__global__ __launch_bounds__(256) void kt_g0(bf16* G0, const bf16* gw0b,
                                             const bf16* d0b, int i0, int ch) {
  const int idx = blockIdx.x * 256 + threadIdx.x;
  if (idx >= ch * 16384) return;
  const int n = idx >> 7, j = (idx & 127) << 3;
  const int d = n & 127;
  const int ig = i0 + (n >> 7);
  const int wsel = (d + 1 < 128) ? d + 1 : 127;   // d==127 pad (masked in B2)
  bf16x8 gv = *(const bf16x8*)(gw0b + wsel * 1024 + j);
  bf16x8 dv = *(const bf16x8*)(d0b + (size_t)ig * 1024 + j);
  bf16x8 v;
#pragma unroll
  for (int e = 0; e < 8; ++e) v[e] = (bf16)((float)gv[e] * (float)dv[e]);
  *(bf16x8*)(G0 + (size_t)n * 1024 + j) = v;
}

__global__ __launch_bounds__(256) void kt_gdot(const bf16* e1b, const float* bdw,
                                               const float* bdb, float* gf, float* gout) {
  const int i = blockIdx.x * 4 + (threadIdx.x >> 6);
  const int lane = threadIdx.x & 63;
  float s = 0.0f;
  for (int k = lane; k < 448; k += 64) s += (float)e1b[(size_t)i * 512 + k] * bdw[k];
#pragma unroll
  for (int off = 32; off > 0; off >>= 1) s += __shfl_down(s, off, 64);
  if (lane == 0) {
    const float v = s + bdb[0];
    gf[i] = v;
    gout[i] = v;
  }
}

__global__ __launch_bounds__(256) void kt_fin(const float* gf, const float* tr,
                                              const float* pp, float* dp) {
  const int i = blockIdx.x * 256 + threadIdx.x;
  if (i < 1024) dp[i] = gf[i] - pp[i] * tr[i];
}

extern "C" void kernel_launch(void* const* d_in, const int* in_sizes, int n_in,
                              void* d_out, int out_size, void* d_ws, size_t ws_size,
                              hipStream_t stream) {
  const float* pt  = (const float*)d_in[0];
  const float* x   = (const float*)d_in[1];
  const float* pp  = (const float*)d_in[3];
  const float* gw0 = (const float*)d_in[4];
  const float* gb0 = (const float*)d_in[5];
  const float* gw1 = (const float*)d_in[6];
  const float* gb1 = (const float*)d_in[7];
  const float* gw2 = (const float*)d_in[8];
  const float* gb2 = (const float*)d_in[9];
  const float* gdw = (const float*)d_in[10];
  const float* gdb = (const float*)d_in[11];
  const float* bw0 = (const float*)d_in[12];
  const float* bb0 = (const float*)d_in[13];
  const float* bw1 = (const float*)d_in[14];
  const float* bb1 = (const float*)d_in[15];
  const float* bdw = (const float*)d_in[16];
  const float* bdb = (const float*)d_in[17];
  float* out = (float*)d_out;

  char* w = (char*)d_ws;
  size_t used = 0;
  auto alloc = [&](size_t nbytes) -> void* {
    void* r = w + used;
    used += (nbytes + 255) & ~(size_t)255;
    return r;
  };
  bf16* gw0b = (bf16*)alloc((size_t)128 * 1024 * 2);
  bf16* gw0t = (bf16*)alloc((size_t)1024 * 128 * 2);
  bf16* gw1t = (bf16*)alloc((size_t)1024 * 1024 * 2);  // [l pad][j], pad rows zero
  bf16* gw2t = (bf16*)alloc((size_t)1024 * 1024 * 2);  // [k' pad][l pad], pad zero
  bf16* gdwt = (bf16*)alloc((size_t)128 * 1024 * 2);
  bf16* bw0t = (bf16*)alloc((size_t)512 * 192 * 2);
  bf16* bw1t = (bf16*)alloc((size_t)512 * 512 * 2);
  bf16* Xg   = (bf16*)alloc((size_t)1024 * 128 * 2);
  bf16* Xb   = (bf16*)alloc((size_t)1024 * 192 * 2);
  bf16* h0b  = (bf16*)alloc((size_t)1024 * 1024 * 2);
  bf16* h1b  = (bf16*)alloc((size_t)1024 * 1024 * 2);
  bf16* h2b  = (bf16*)alloc((size_t)1024 * 1024 * 2);
  bf16* e0b  = (bf16*)alloc((size_t)1024 * 512 * 2);
  bf16* e1b  = (bf16*)alloc((size_t)1024 * 512 * 2);
  bf16* d0b  = (bf16*)alloc((size_t)1024 * 1024 * 2);
  bf16* d1b  = (bf16*)alloc((size_t)1024 * 960 * 2);
  bf16* d2b  = (bf16*)alloc((size_t)1024 * 896 * 2);
  float* gf  = (float*)alloc(1024 * 4);
  float* tr  = (float*)alloc(1024 * 4);

  const size_t perSample = (size_t)128 * 1024 * 2;     // 256 KB
  size_t avail = (ws_size > used) ? ws_size - used : 0;
  int CH = (int)(avail / (2 * perSample));             // G0 + Upr per sample
  if (CH > 256) CH = 256;   // keep per-chunk G0+Upr (~134 MB) L3-resident
  if (CH < 1) CH = 1;
  bf16* G0  = (bf16*)alloc((size_t)CH * perSample);
  bf16* Upr = (bf16*)(w + used);

  hipMemsetAsync(tr, 0, 1024 * 4, stream);

  kt_convert<<<dim3(512), 256, 0, stream>>>(gw0b, gw0, 128 * 1024);
  kt_transpose<<<dim3(512), 256, 0, stream>>>(gw0t, gw0, 128, 1024, 128, 1024);
  kt_transpose<<<dim3(4096), 256, 0, stream>>>(gw1t, gw1, 1024, 960, 1024, 1024);
  kt_transpose<<<dim3(4096), 256, 0, stream>>>(gw2t, gw2, 960, 896, 1024, 1024);
  kt_transpose<<<dim3(512), 256, 0, stream>>>(gdwt, gdw, 896, 128, 1024, 128);
  kt_transpose<<<dim3(384), 256, 0, stream>>>(bw0t, bw0, 129, 512, 192, 512);
  kt_transpose<<<dim3(1024), 256, 0, stream>>>(bw1t, bw1, 512, 448, 512, 512);
  kt_build<<<dim3(768), 256, 0, stream>>>(pt, x, Xg, Xb);

  {  // L0
    FArgs a{}; a.A = Xg; a.lda = 128; a.Bt = gw0t; a.ldb = 128; a.bias = gb0;
    a.C = h0b; a.ldc = 1024; a.D = d0b; a.ldd = 1024; a.K = 128; a.realN = 1024;
    kt_fwd<1><<<dim3(8, 8), 256, 0, stream>>>(a);
  }
  {  // L1
    FArgs a{}; a.A = h0b; a.lda = 1024; a.Bt = gw1t; a.ldb = 1024; a.bias = gb1;
    a.C = h1b; a.ldc = 1024; a.D = d1b; a.ldd = 960; a.K = 1024; a.realN = 960;
    kt_fwd<1><<<dim3(8, 8), 256, 0, stream>>>(a);
  }
  {  // L2
    FArgs a{}; a.A = h1b; a.lda = 1024; a.Bt = gw2t; a.ldb = 1024; a.bias = gb2;
    a.C = h2b; a.ldc = 1024; a.D = d2b; a.ldd = 896; a.K = 1024; a.realN = 896;
    kt_fwd<1><<<dim3(8, 7), 256, 0, stream>>>(a);
  }
  {  // dx_dt
    FArgs a{}; a.A = h2b; a.lda = 1024; a.Bt = gdwt; a.ldb = 1024; a.bias = gdb;
    a.outF = out; a.ldo = 128; a.K = 896; a.realN = 128;
    kt_fwd<0><<<dim3(8, 1), 256, 0, stream>>>(a);
  }
  {  // e0
    FArgs a{}; a.A = Xb; a.lda = 192; a.Bt = bw0t; a.ldb = 192; a.bias = bb0;
    a.C = e0b; a.ldc = 512; a.K = 192; a.realN = 512;
    kt_fwd<1><<<dim3(8, 4), 256, 0, stream>>>(a);
  }
  {  // e1
    FArgs a{}; a.A = e0b; a.lda = 512; a.Bt = bw1t; a.ldb = 512; a.bias = bb1;
    a.C = e1b; a.ldc = 512; a.K = 512; a.realN = 448;
    kt_fwd<1><<<dim3(8, 4), 256, 0, stream>>>(a);
  }
  kt_gdot<<<dim3(256), 256, 0, stream>>>(e1b, bdw, bdb, gf, out + 131072);

  for (int i0 = 0; i0 < 1024; i0 += CH) {
    const int ch = (1024 - i0 < CH) ? (1024 - i0) : CH;
    kt_g0<<<dim3((ch * 16384 + 255) / 256), 256, 0, stream>>>(G0, gw0b, d0b, i0, ch);
    {  // B1: U' = D1 * (gw1^T @ G0)
      TArgs a{}; a.A = gw1t; a.B = G0; a.d1b = d1b; a.Upr = Upr; a.i0 = i0;
      kt_tile<0><<<dim3(4, ch), 256, 0, stream>>>(a);
    }
    {  // B2: trace reduce of gw2^T @ U'
      TArgs a{}; a.A = gw2t; a.B = Upr; a.d2b = d2b; a.gdw = gdw; a.tr = tr; a.i0 = i0;
      kt_tile<1><<<dim3(4, ch), 256, 0, stream>>>(a);
    }
  }

  kt_fin<<<dim3(4), 256, 0, stream>>>(gf, tr, pp, out + 132096);
}

// Round 10
// 991.194 us; speedup vs baseline: 17.2614x; 1.1518x over previous
//
#include <hip/hip_runtime.h>

// R10: occupancy-tuned trace GEMMs.
// - kt_tile 128x128 (acc 4x4 = 64 AGPR + ~88 VGPR -> 3 waves/SIMD, 3 blocks/CU;
//   R9's 256-tile had 128 AGPR -> 2 waves/SIMD, the measured 21% occupancy cap)
// - CH=256 kept: B-side m-tile re-reads stay L3-resident (R9-proven)
// - B2: grid 7 (M=896 exact) and K=960 (drop pad FLOPs: -14%/-6.7%)
// - 7 prep kernels fused into one kt_prep dispatch
// Proven: fp32 in/out, documented order, ws >= ~280 MB, trace math, CH arith.

typedef __bf16 bf16;
typedef __bf16 bf16x8 __attribute__((ext_vector_type(8)));
typedef float floatx4 __attribute__((ext_vector_type(4)));

#if defined(__has_builtin)
#if __has_builtin(__builtin_amdgcn_global_load_lds)
#define HAVE_GLL 1
#endif
#endif

typedef __attribute__((address_space(3))) char lds_char_t;
typedef __attribute__((address_space(1))) const char gbl_char_t;

__device__ inline void async_load16(const void* gp, void* lp) {
#ifdef HAVE_GLL
  __builtin_amdgcn_global_load_lds((gbl_char_t*)gp, (lds_char_t*)lp, 16, 0, 0);
#else
  *(bf16x8*)lp = *(const bf16x8*)gp;
#endif
}

// Stage a 128x64 bf16 tile into LDS with XOR-by-row chunk swizzle.
__device__ inline void stage_async(const bf16* src, long row0, int ld, int kc,
                                   bf16* dst, int wid, int sr8, int cph) {
#pragma unroll
  for (int t = 0; t < 4; ++t) {
    const int r = (wid * 4 + t) * 8 + sr8;
    const int csrc = (cph - r) & 7;
    async_load16(src + (row0 + r) * (size_t)ld + kc + csrc * 8,
                 dst + r * 64 + cph * 8);
  }
}

__device__ inline void mfma_block(const bf16* As, const bf16* Bs,
                                  floatx4 (&acc)[4][4], int wm, int wn,
                                  int l16, int quad) {
#pragma unroll
  for (int ks = 0; ks < 2; ++ks) {
    bf16x8 af[4], bfv[4];
#pragma unroll
    for (int mt = 0; mt < 4; ++mt) {
      const int r = wm * 64 + mt * 16 + l16;
      const int c = (ks * 4 + quad + r) & 7;
      af[mt] = *(const bf16x8*)(As + r * 64 + c * 8);
    }
#pragma unroll
    for (int nt = 0; nt < 4; ++nt) {
      const int r = wn * 64 + nt * 16 + l16;
      const int c = (ks * 4 + quad + r) & 7;
      bfv[nt] = *(const bf16x8*)(Bs + r * 64 + c * 8);
    }
#pragma unroll
    for (int mt = 0; mt < 4; ++mt)
#pragma unroll
      for (int nt = 0; nt < 4; ++nt)
        acc[mt][nt] = __builtin_amdgcn_mfma_f32_16x16x32_bf16(af[mt], bfv[nt], acc[mt][nt], 0, 0, 0);
  }
}

// ---------------- trace GEMMs (128x128, 3 blocks/CU) ----------------
struct TArgs {
  const bf16* A;        // [1024][1024] (gw1t / gw2t, zero-padded)
  const bf16* B;        // [ch*128][1024] (G0 for B1, Upr for B2)
  const bf16* d1b;      // B1: [1024][960]
  bf16* Upr;            // B1 out: [ch*128][1024]
  const bf16* d2b;      // B2: [1024][896]
  const float* gdw;     // B2: [896][128] fp32
  float* tr;            // [1024]
  int i0; int K;
};

// MODE 0 = B1: U' rows = d1 * (gw1^T @ G0-rows); MODE 1 = B2: trace reduce.
template <int MODE>
__global__ __launch_bounds__(256, 3) void kt_tile(TArgs p) {
  __shared__ __align__(16) char lds[34816];   // As16K+Bs16K; MODE0 bounce 128*136*2
  bf16* As = (bf16*)lds;
  bf16* Bs = As + 8192;
  bf16* bounce = (bf16*)lds;
  __shared__ float red4[4];

  const int tid  = threadIdx.x;
  const int wid  = tid >> 6, lane = tid & 63;
  const int wm   = wid & 1, wn = wid >> 1;
  const int quad = lane >> 4, l16 = lane & 15;
  const int sr8  = lane >> 3, cph = lane & 7;
  const int m0   = blockIdx.x * 128;
  const int nb   = blockIdx.y;
  const int ig   = p.i0 + nb;
  const int n0   = nb * 128;

  floatx4 acc[4][4];
#pragma unroll
  for (int a = 0; a < 4; ++a)
#pragma unroll
    for (int b = 0; b < 4; ++b)
#pragma unroll
      for (int r = 0; r < 4; ++r) acc[a][b][r] = 0.0f;

  for (int kc = 0; kc < p.K; kc += 64) {
    stage_async(p.A, m0, 1024, kc, As, wid, sr8, cph);
    stage_async(p.B, n0, 1024, kc, Bs, wid, sr8, cph);
    __syncthreads();
    mfma_block(As, Bs, acc, wm, wn, l16, quad);
    __syncthreads();
  }

  if (MODE == 0) {
#pragma unroll
    for (int nt = 0; nt < 4; ++nt) {
      const int nl = wn * 64 + nt * 16 + l16;
#pragma unroll
      for (int mt = 0; mt < 4; ++mt)
#pragma unroll
        for (int r = 0; r < 4; ++r) {
          const int ml = wm * 64 + mt * 16 + quad * 4 + r;
          const int mg = m0 + ml;
          const float d1v = (mg < 960) ? (float)p.d1b[(size_t)ig * 960 + mg] : 0.0f;
          bounce[nl * 136 + ml] = (bf16)(acc[mt][nt][r] * d1v);
        }
    }
    __syncthreads();
    const int r2 = tid >> 1, half16 = tid & 1;
#pragma unroll
    for (int c = 0; c < 8; ++c) {
      const int ch16 = half16 * 8 + c;
      bf16x8 v = *(const bf16x8*)(bounce + r2 * 136 + ch16 * 8);
      *(bf16x8*)(p.Upr + (size_t)(n0 + r2) * 1024 + m0 + ch16 * 8) = v;
    }
  } else {
    float s = 0.0f;
#pragma unroll
    for (int nt = 0; nt < 4; ++nt) {
      const int d = wn * 64 + nt * 16 + l16;
      if (d < 127) {
#pragma unroll
        for (int mt = 0; mt < 4; ++mt)
#pragma unroll
          for (int r = 0; r < 4; ++r) {
            const int mg = m0 + wm * 64 + mt * 16 + quad * 4 + r;  // < 896 (grid 7)
            const float w = (float)p.d2b[(size_t)ig * 896 + mg] * p.gdw[mg * 128 + d];
            s += acc[mt][nt][r] * w;
          }
      }
    }
#pragma unroll
    for (int off = 1; off < 64; off <<= 1) s += __shfl_xor(s, off, 64);
    if (lane == 0) red4[wid] = s;
    __syncthreads();
    if (tid == 0) atomicAdd(p.tr + ig, red4[0] + red4[1] + red4[2] + red4[3]);
  }
}

// ---------------- forward GEMMs ----------------
struct FArgs {
  const bf16* A; int lda;
  const bf16* Bt; int ldb;
  const float* bias;
  bf16* C; int ldc;
  bf16* D; int ldd;
  float* outF; int ldo;
  int K; int realN;
};

template <int ACT>
__global__ __launch_bounds__(256) void kt_fwd(FArgs p) {
  __shared__ __align__(16) bf16 As[8192];
  __shared__ __align__(16) bf16 Bs[8192];
  const int tid  = threadIdx.x;
  const int wid  = tid >> 6, lane = tid & 63;
  const int wm   = wid & 1, wn = wid >> 1;
  const int quad = lane >> 4, l16 = lane & 15;
  const int sr8  = lane >> 3, cph = lane & 7;
  const int m0   = blockIdx.x * 128;
  const int bn0  = blockIdx.y * 128;

  floatx4 acc[4][4];
#pragma unroll
  for (int a = 0; a < 4; ++a)
#pragma unroll
    for (int b = 0; b < 4; ++b)
#pragma unroll
      for (int r = 0; r < 4; ++r) acc[a][b][r] = 0.0f;

  for (int kc = 0; kc < p.K; kc += 64) {
    stage_async(p.A, m0, p.lda, kc, As, wid, sr8, cph);
    stage_async(p.Bt, bn0, p.ldb, kc, Bs, wid, sr8, cph);
    __syncthreads();
    mfma_block(As, Bs, acc, wm, wn, l16, quad);
    __syncthreads();
  }

#pragma unroll
  for (int nt = 0; nt < 4; ++nt) {
    const int ng = bn0 + wn * 64 + nt * 16 + l16;
    const float bv = (ng < p.realN) ? p.bias[ng] : 0.0f;
#pragma unroll
    for (int mt = 0; mt < 4; ++mt)
#pragma unroll
      for (int r = 0; r < 4; ++r) {
        const int i = m0 + wm * 64 + mt * 16 + quad * 4 + r;
        const float v = acc[mt][nt][r] + bv;
        if (ACT) {
          const float t = tanhf(v);
          p.C[(size_t)i * p.ldc + ng] = (ng < p.realN) ? (bf16)t : (bf16)0.0f;
          if (p.D && ng < p.realN)
            p.D[(size_t)i * p.ldd + ng] = (bf16)(1.0f - t * t);
        } else if (ng < p.realN) {
          p.outF[(size_t)i * p.ldo + ng] = v;
        }
      }
  }
}

// ---------------- fused prep (transposes + convert + build) ----------------
struct PArgs {
  const float *gw0, *gw1, *gw2, *gdw, *bw0, *bw1, *pt, *x;
  bf16 *gw0b, *gw0t, *gw1t, *gw2t, *gdwt, *bw0t, *bw1t, *Xg, *Xb;
};

__device__ inline void tpose(bf16* dst, const float* src, int R, int C,
                             int ldd, int idx) {
  const int c = idx / ldd, r = idx % ldd;
  dst[idx] = (c < C && r < R) ? (bf16)src[(size_t)r * C + c] : (bf16)0.0f;
}

__global__ __launch_bounds__(256) void kt_prep(PArgs p) {
  int b = blockIdx.x;
  const int t = threadIdx.x;
  if (b < 512) { p.gw0b[b * 256 + t] = (bf16)p.gw0[b * 256 + t]; return; }
  b -= 512;
  if (b < 512) { tpose(p.gw0t, p.gw0, 128, 1024, 128, b * 256 + t); return; }
  b -= 512;
  if (b < 4096) { tpose(p.gw1t, p.gw1, 1024, 960, 1024, b * 256 + t); return; }
  b -= 4096;
  if (b < 4096) { tpose(p.gw2t, p.gw2, 960, 896, 1024, b * 256 + t); return; }
  b -= 4096;
  if (b < 512) { tpose(p.gdwt, p.gdw, 896, 128, 1024, b * 256 + t); return; }
  b -= 512;
  if (b < 384) { tpose(p.bw0t, p.bw0, 129, 512, 192, b * 256 + t); return; }
  b -= 384;
  if (b < 1024) { tpose(p.bw1t, p.bw1, 512, 448, 512, b * 256 + t); return; }
  b -= 1024;
  {  // build Xg/Xb: 768 blocks, idx over 1024*192
    const int idx = b * 256 + t;
    const int i = idx / 192, c = idx % 192;
    const float s = p.pt[0];
    float vb;
    if (c == 0) vb = s;
    else if (c <= 128) vb = p.x[i * 128 + c - 1];
    else vb = 0.0f;
    p.Xb[i * 192 + c] = (bf16)vb;
    if (c < 128) p.Xg[i * 128 + c] = (bf16)((c == 0) ? s : p.x[i * 128 + c - 1]);
  }
}

// ---------------- small helpers ----------------
__global__ __launch_bounds__(256) void kt_g0(bf16* G0, const bf16* gw0b,
                                             const bf16* d0b, int i0, int ch) {
  const int idx = blockIdx.x * 256 + threadIdx.x;
  if (idx >= ch * 16384) return;
  const int n = idx >> 7, j = (idx & 127) << 3;
  const int d = n & 127;
  const int ig = i0 + (n >> 7);
  const int wsel = (d + 1 < 128) ? d + 1 : 127;   // d==127 pad (masked in B2)
  bf16x8 gv = *(const bf16x8*)(gw0b + wsel * 1024 + j);
  bf16x8 dv = *(const bf16x8*)(d0b + (size_t)ig * 1024 + j);
  bf16x8 v;
#pragma unroll
  for (int e = 0; e < 8; ++e) v[e] = (bf16)((float)gv[e] * (float)dv[e]);
  *(bf16x8*)(G0 + (size_t)n * 1024 + j) = v;
}

__global__ __launch_bounds__(256) void kt_gdot(const bf16* e1b, const float* bdw,
                                               const float* bdb, float* gf, float* gout) {
  const int i = blockIdx.x * 4 + (threadIdx.x >> 6);
  const int lane = threadIdx.x & 63;
  float s = 0.0f;
  for (int k = lane; k < 448; k += 64) s += (float)e1b[(size_t)i * 512 + k] * bdw[k];
#pragma unroll
  for (int off = 32; off > 0; off >>= 1) s += __shfl_down(s, off, 64);
  if (lane == 0) {
    const float v = s + bdb[0];
    gf[i] = v;
    gout[i] = v;
  }
}

__global__ __launch_bounds__(256) void kt_fin(const float* gf, const float* tr,
                                              const float* pp, float* dp) {
  const int i = blockIdx.x * 256 + threadIdx.x;
  if (i < 1024) dp[i] = gf[i] - pp[i] * tr[i];
}

extern "C" void kernel_launch(void* const* d_in, const int* in_sizes, int n_in,
                              void* d_out, int out_size, void* d_ws, size_t ws_size,
                              hipStream_t stream) {
  const float* pt  = (const float*)d_in[0];
  const float* x   = (const float*)d_in[1];
  const float* pp  = (const float*)d_in[3];
  const float* gw0 = (const float*)d_in[4];
  const float* gb0 = (const float*)d_in[5];
  const float* gw1 = (const float*)d_in[6];
  const float* gb1 = (const float*)d_in[7];
  const float* gw2 = (const float*)d_in[8];
  const float* gb2 = (const float*)d_in[9];
  const float* gdw = (const float*)d_in[10];
  const float* gdb = (const float*)d_in[11];
  const float* bw0 = (const float*)d_in[12];
  const float* bb0 = (const float*)d_in[13];
  const float* bw1 = (const float*)d_in[14];
  const float* bb1 = (const float*)d_in[15];
  const float* bdw = (const float*)d_in[16];
  const float* bdb = (const float*)d_in[17];
  float* out = (float*)d_out;

  char* w = (char*)d_ws;
  size_t used = 0;
  auto alloc = [&](size_t nbytes) -> void* {
    void* r = w + used;
    used += (nbytes + 255) & ~(size_t)255;
    return r;
  };
  bf16* gw0b = (bf16*)alloc((size_t)128 * 1024 * 2);
  bf16* gw0t = (bf16*)alloc((size_t)1024 * 128 * 2);
  bf16* gw1t = (bf16*)alloc((size_t)1024 * 1024 * 2);
  bf16* gw2t = (bf16*)alloc((size_t)1024 * 1024 * 2);
  bf16* gdwt = (bf16*)alloc((size_t)128 * 1024 * 2);
  bf16* bw0t = (bf16*)alloc((size_t)512 * 192 * 2);
  bf16* bw1t = (bf16*)alloc((size_t)512 * 512 * 2);
  bf16* Xg   = (bf16*)alloc((size_t)1024 * 128 * 2);
  bf16* Xb   = (bf16*)alloc((size_t)1024 * 192 * 2);
  bf16* h0b  = (bf16*)alloc((size_t)1024 * 1024 * 2);
  bf16* h1b  = (bf16*)alloc((size_t)1024 * 1024 * 2);
  bf16* h2b  = (bf16*)alloc((size_t)1024 * 1024 * 2);
  bf16* e0b  = (bf16*)alloc((size_t)1024 * 512 * 2);
  bf16* e1b  = (bf16*)alloc((size_t)1024 * 512 * 2);
  bf16* d0b  = (bf16*)alloc((size_t)1024 * 1024 * 2);
  bf16* d1b  = (bf16*)alloc((size_t)1024 * 960 * 2);
  bf16* d2b  = (bf16*)alloc((size_t)1024 * 896 * 2);
  float* gf  = (float*)alloc(1024 * 4);
  float* tr  = (float*)alloc(1024 * 4);

  const size_t perSample = (size_t)128 * 1024 * 2;     // 256 KB
  size_t avail = (ws_size > used) ? ws_size - used : 0;
  int CH = (int)(avail / (2 * perSample));
  if (CH > 256) CH = 256;   // keep per-chunk G0+Upr (~134 MB) L3-resident
  if (CH < 1) CH = 1;
  bf16* G0  = (bf16*)alloc((size_t)CH * perSample);
  bf16* Upr = (bf16*)(w + used);

  hipMemsetAsync(tr, 0, 1024 * 4, stream);

  {
    PArgs a{gw0, gw1, gw2, gdw, bw0, bw1, pt, x,
            gw0b, gw0t, gw1t, gw2t, gdwt, bw0t, bw1t, Xg, Xb};
    kt_prep<<<dim3(11904), 256, 0, stream>>>(a);
  }

  {  // L0
    FArgs a{}; a.A = Xg; a.lda = 128; a.Bt = gw0t; a.ldb = 128; a.bias = gb0;
    a.C = h0b; a.ldc = 1024; a.D = d0b; a.ldd = 1024; a.K = 128; a.realN = 1024;
    kt_fwd<1><<<dim3(8, 8), 256, 0, stream>>>(a);
  }
  {  // L1
    FArgs a{}; a.A = h0b; a.lda = 1024; a.Bt = gw1t; a.ldb = 1024; a.bias = gb1;
    a.C = h1b; a.ldc = 1024; a.D = d1b; a.ldd = 960; a.K = 1024; a.realN = 960;
    kt_fwd<1><<<dim3(8, 8), 256, 0, stream>>>(a);
  }
  {  // L2
    FArgs a{}; a.A = h1b; a.lda = 1024; a.Bt = gw2t; a.ldb = 1024; a.bias = gb2;
    a.C = h2b; a.ldc = 1024; a.D = d2b; a.ldd = 896; a.K = 1024; a.realN = 896;
    kt_fwd<1><<<dim3(8, 7), 256, 0, stream>>>(a);
  }
  {  // dx_dt
    FArgs a{}; a.A = h2b; a.lda = 1024; a.Bt = gdwt; a.ldb = 1024; a.bias = gdb;
    a.outF = out; a.ldo = 128; a.K = 896; a.realN = 128;
    kt_fwd<0><<<dim3(8, 1), 256, 0, stream>>>(a);
  }
  {  // e0
    FArgs a{}; a.A = Xb; a.lda = 192; a.Bt = bw0t; a.ldb = 192; a.bias = bb0;
    a.C = e0b; a.ldc = 512; a.K = 192; a.realN = 512;
    kt_fwd<1><<<dim3(8, 4), 256, 0, stream>>>(a);
  }
  {  // e1
    FArgs a{}; a.A = e0b; a.lda = 512; a.Bt = bw1t; a.ldb = 512; a.bias = bb1;
    a.C = e1b; a.ldc = 512; a.K = 512; a.realN = 448;
    kt_fwd<1><<<dim3(8, 4), 256, 0, stream>>>(a);
  }
  kt_gdot<<<dim3(256), 256, 0, stream>>>(e1b, bdw, bdb, gf, out + 131072);

  for (int i0 = 0; i0 < 1024; i0 += CH) {
    const int ch = (1024 - i0 < CH) ? (1024 - i0) : CH;
    kt_g0<<<dim3((ch * 16384 + 255) / 256), 256, 0, stream>>>(G0, gw0b, d0b, i0, ch);
    {  // B1: U' = D1 * (gw1^T @ G0), M pad 1024, K=1024
      TArgs a{}; a.A = gw1t; a.B = G0; a.d1b = d1b; a.Upr = Upr; a.i0 = i0; a.K = 1024;
      kt_tile<0><<<dim3(8, ch), 256, 0, stream>>>(a);
    }
    {  // B2: trace reduce of gw2^T @ U', M=896 exact, K=960 exact
      TArgs a{}; a.A = gw2t; a.B = Upr; a.d2b = d2b; a.gdw = gdw; a.tr = tr;
      a.i0 = i0; a.K = 960;
      kt_tile<1><<<dim3(7, ch), 256, 0, stream>>>(a);
    }
  }

  kt_fin<<<dim3(4), 256, 0, stream>>>(gf, tr, pp, out + 132096);
}

// Round 11
// 875.779 us; speedup vs baseline: 19.5362x; 1.1318x over previous
//
#include <hip/hip_runtime.h>

// R11: XCD-aware swizzle for the trace GEMMs.
// Consecutive blockIdx round-robin across the 8 XCDs (per-XCD L2s are
// private), so R10's layout put the 8 m-blocks sharing one sample's B-tile on
// 8 DIFFERENT XCDs -> 8 L2 copies -> B-side streamed past L2 (265 MB
// FETCH/dispatch, 39% HBM). Remap: xcd = nb%8, m-tiles of one sample
// consecutive in the per-XCD queue -> B-tile fetched once per sample, 8x L2
// reuse (~3 MB concurrent footprint per XCD < 4 MB L2).
// CH=192: B1 grid 1536 = exactly 2 full occupancy waves (768 slots @ 3/CU).
// Proven: fp32 in/out, documented order, ws >= ~280 MB, trace math.

typedef __bf16 bf16;
typedef __bf16 bf16x8 __attribute__((ext_vector_type(8)));
typedef float floatx4 __attribute__((ext_vector_type(4)));

#if defined(__has_builtin)
#if __has_builtin(__builtin_amdgcn_global_load_lds)
#define HAVE_GLL 1
#endif
#endif

typedef __attribute__((address_space(3))) char lds_char_t;
typedef __attribute__((address_space(1))) const char gbl_char_t;

__device__ inline void async_load16(const void* gp, void* lp) {
#ifdef HAVE_GLL
  __builtin_amdgcn_global_load_lds((gbl_char_t*)gp, (lds_char_t*)lp, 16, 0, 0);
#else
  *(bf16x8*)lp = *(const bf16x8*)gp;
#endif
}

// Stage a 128x64 bf16 tile into LDS with XOR-by-row chunk swizzle.
__device__ inline void stage_async(const bf16* src, long row0, int ld, int kc,
                                   bf16* dst, int wid, int sr8, int cph) {
#pragma unroll
  for (int t = 0; t < 4; ++t) {
    const int r = (wid * 4 + t) * 8 + sr8;
    const int csrc = (cph - r) & 7;
    async_load16(src + (row0 + r) * (size_t)ld + kc + csrc * 8,
                 dst + r * 64 + cph * 8);
  }
}

__device__ inline void mfma_block(const bf16* As, const bf16* Bs,
                                  floatx4 (&acc)[4][4], int wm, int wn,
                                  int l16, int quad) {
#pragma unroll
  for (int ks = 0; ks < 2; ++ks) {
    bf16x8 af[4], bfv[4];
#pragma unroll
    for (int mt = 0; mt < 4; ++mt) {
      const int r = wm * 64 + mt * 16 + l16;
      const int c = (ks * 4 + quad + r) & 7;
      af[mt] = *(const bf16x8*)(As + r * 64 + c * 8);
    }
#pragma unroll
    for (int nt = 0; nt < 4; ++nt) {
      const int r = wn * 64 + nt * 16 + l16;
      const int c = (ks * 4 + quad + r) & 7;
      bfv[nt] = *(const bf16x8*)(Bs + r * 64 + c * 8);
    }
#pragma unroll
    for (int mt = 0; mt < 4; ++mt)
#pragma unroll
      for (int nt = 0; nt < 4; ++nt)
        acc[mt][nt] = __builtin_amdgcn_mfma_f32_16x16x32_bf16(af[mt], bfv[nt], acc[mt][nt], 0, 0, 0);
  }
}

// ---------------- trace GEMMs (128x128, XCD-swizzled 1D grid) ----------------
struct TArgs {
  const bf16* A;        // [1024][1024] (gw1t / gw2t, zero-padded)
  const bf16* B;        // [ch*128][1024] (G0 for B1, Upr for B2)
  const bf16* d1b;      // B1: [1024][960]
  bf16* Upr;            // B1 out: [ch*128][1024]
  const bf16* d2b;      // B2: [1024][896]
  const float* gdw;     // B2: [896][128] fp32
  float* tr;            // [1024]
  int i0; int K; int ch;
};

// MODE 0 = B1: U' rows = d1 * (gw1^T @ G0-rows); MODE 1 = B2: trace reduce.
template <int MODE>
__global__ __launch_bounds__(256, 3) void kt_tile(TArgs p) {
  // XCD swizzle: xcd = idx&7 == nb&7; m-tiles of one nb consecutive per-XCD.
  const int idx = blockIdx.x;
  const int mt8 = (idx >> 3) & 7;
  const int nb  = ((idx >> 6) << 3) + (idx & 7);
  if (nb >= p.ch) return;
  if (MODE == 1 && mt8 == 7) return;        // B2 has 7 m-tiles (M=896)

  __shared__ __align__(16) char lds[34816];
  bf16* As = (bf16*)lds;
  bf16* Bs = As + 8192;
  bf16* bounce = (bf16*)lds;
  __shared__ float red4[4];

  const int tid  = threadIdx.x;
  const int wid  = tid >> 6, lane = tid & 63;
  const int wm   = wid & 1, wn = wid >> 1;
  const int quad = lane >> 4, l16 = lane & 15;
  const int sr8  = lane >> 3, cph = lane & 7;
  const int m0   = mt8 * 128;
  const int ig   = p.i0 + nb;
  const int n0   = nb * 128;

  floatx4 acc[4][4];
#pragma unroll
  for (int a = 0; a < 4; ++a)
#pragma unroll
    for (int b = 0; b < 4; ++b)
#pragma unroll
      for (int r = 0; r < 4; ++r) acc[a][b][r] = 0.0f;

  for (int kc = 0; kc < p.K; kc += 64) {
    stage_async(p.A, m0, 1024, kc, As, wid, sr8, cph);
    stage_async(p.B, n0, 1024, kc, Bs, wid, sr8, cph);
    __syncthreads();
    mfma_block(As, Bs, acc, wm, wn, l16, quad);
    __syncthreads();
  }

  if (MODE == 0) {
#pragma unroll
    for (int nt = 0; nt < 4; ++nt) {
      const int nl = wn * 64 + nt * 16 + l16;
#pragma unroll
      for (int mt = 0; mt < 4; ++mt)
#pragma unroll
        for (int r = 0; r < 4; ++r) {
          const int ml = wm * 64 + mt * 16 + quad * 4 + r;
          const int mg = m0 + ml;
          const float d1v = (mg < 960) ? (float)p.d1b[(size_t)ig * 960 + mg] : 0.0f;
          bounce[nl * 136 + ml] = (bf16)(acc[mt][nt][r] * d1v);
        }
    }
    __syncthreads();
    const int r2 = tid >> 1, half16 = tid & 1;
#pragma unroll
    for (int c = 0; c < 8; ++c) {
      const int ch16 = half16 * 8 + c;
      bf16x8 v = *(const bf16x8*)(bounce + r2 * 136 + ch16 * 8);
      *(bf16x8*)(p.Upr + (size_t)(n0 + r2) * 1024 + m0 + ch16 * 8) = v;
    }
  } else {
    float s = 0.0f;
#pragma unroll
    for (int nt = 0; nt < 4; ++nt) {
      const int d = wn * 64 + nt * 16 + l16;
      if (d < 127) {
#pragma unroll
        for (int mt = 0; mt < 4; ++mt)
#pragma unroll
          for (int r = 0; r < 4; ++r) {
            const int mg = m0 + wm * 64 + mt * 16 + quad * 4 + r;  // < 896
            const float w = (float)p.d2b[(size_t)ig * 896 + mg] * p.gdw[mg * 128 + d];
            s += acc[mt][nt][r] * w;
          }
      }
    }
#pragma unroll
    for (int off = 1; off < 64; off <<= 1) s += __shfl_xor(s, off, 64);
    if (lane == 0) red4[wid] = s;
    __syncthreads();
    if (tid == 0) atomicAdd(p.tr + ig, red4[0] + red4[1] + red4[2] + red4[3]);
  }
}

// ---------------- forward GEMMs ----------------
struct FArgs {
  const bf16* A; int lda;
  const bf16* Bt; int ldb;
  const float* bias;
  bf16* C; int ldc;
  bf16* D; int ldd;
  float* outF; int ldo;
  int K; int realN;
};

template <int ACT>
__global__ __launch_bounds__(256) void kt_fwd(FArgs p) {
  __shared__ __align__(16) bf16 As[8192];
  __shared__ __align__(16) bf16 Bs[8192];
  const int tid  = threadIdx.x;
  const int wid  = tid >> 6, lane = tid & 63;
  const int wm   = wid & 1, wn = wid >> 1;
  const int quad = lane >> 4, l16 = lane & 15;
  const int sr8  = lane >> 3, cph = lane & 7;
  const int m0   = blockIdx.x * 128;
  const int bn0  = blockIdx.y * 128;

  floatx4 acc[4][4];
#pragma unroll
  for (int a = 0; a < 4; ++a)
#pragma unroll
    for (int b = 0; b < 4; ++b)
#pragma unroll
      for (int r = 0; r < 4; ++r) acc[a][b][r] = 0.0f;

  for (int kc = 0; kc < p.K; kc += 64) {
    stage_async(p.A, m0, p.lda, kc, As, wid, sr8, cph);
    stage_async(p.Bt, bn0, p.ldb, kc, Bs, wid, sr8, cph);
    __syncthreads();
    mfma_block(As, Bs, acc, wm, wn, l16, quad);
    __syncthreads();
  }

#pragma unroll
  for (int nt = 0; nt < 4; ++nt) {
    const int ng = bn0 + wn * 64 + nt * 16 + l16;
    const float bv = (ng < p.realN) ? p.bias[ng] : 0.0f;
#pragma unroll
    for (int mt = 0; mt < 4; ++mt)
#pragma unroll
      for (int r = 0; r < 4; ++r) {
        const int i = m0 + wm * 64 + mt * 16 + quad * 4 + r;
        const float v = acc[mt][nt][r] + bv;
        if (ACT) {
          const float t = tanhf(v);
          p.C[(size_t)i * p.ldc + ng] = (ng < p.realN) ? (bf16)t : (bf16)0.0f;
          if (p.D && ng < p.realN)
            p.D[(size_t)i * p.ldd + ng] = (bf16)(1.0f - t * t);
        } else if (ng < p.realN) {
          p.outF[(size_t)i * p.ldo + ng] = v;
        }
      }
  }
}

// ---------------- fused prep ----------------
struct PArgs {
  const float *gw0, *gw1, *gw2, *gdw, *bw0, *bw1, *pt, *x;
  bf16 *gw0b, *gw0t, *gw1t, *gw2t, *gdwt, *bw0t, *bw1t, *Xg, *Xb;
};

__device__ inline void tpose(bf16* dst, const float* src, int R, int C,
                             int ldd, int idx) {
  const int c = idx / ldd, r = idx % ldd;
  dst[idx] = (c < C && r < R) ? (bf16)src[(size_t)r * C + c] : (bf16)0.0f;
}

__global__ __launch_bounds__(256) void kt_prep(PArgs p) {
  int b = blockIdx.x;
  const int t = threadIdx.x;
  if (b < 512) { p.gw0b[b * 256 + t] = (bf16)p.gw0[b * 256 + t]; return; }
  b -= 512;
  if (b < 512) { tpose(p.gw0t, p.gw0, 128, 1024, 128, b * 256 + t); return; }
  b -= 512;
  if (b < 4096) { tpose(p.gw1t, p.gw1, 1024, 960, 1024, b * 256 + t); return; }
  b -= 4096;
  if (b < 4096) { tpose(p.gw2t, p.gw2, 960, 896, 1024, b * 256 + t); return; }
  b -= 4096;
  if (b < 512) { tpose(p.gdwt, p.gdw, 896, 128, 1024, b * 256 + t); return; }
  b -= 512;
  if (b < 384) { tpose(p.bw0t, p.bw0, 129, 512, 192, b * 256 + t); return; }
  b -= 384;
  if (b < 1024) { tpose(p.bw1t, p.bw1, 512, 448, 512, b * 256 + t); return; }
  b -= 1024;
  {
    const int idx = b * 256 + t;
    const int i = idx / 192, c = idx % 192;
    const float s = p.pt[0];
    float vb;
    if (c == 0) vb = s;
    else if (c <= 128) vb = p.x[i * 128 + c - 1];
    else vb = 0.0f;
    p.Xb[i * 192 + c] = (bf16)vb;
    if (c < 128) p.Xg[i * 128 + c] = (bf16)((c == 0) ? s : p.x[i * 128 + c - 1]);
  }
}

// ---------------- small helpers ----------------
__global__ __launch_bounds__(256) void kt_g0(bf16* G0, const bf16* gw0b,
                                             const bf16* d0b, int i0, int ch) {
  const int idx = blockIdx.x * 256 + threadIdx.x;
  if (idx >= ch * 16384) return;
  const int n = idx >> 7, j = (idx & 127) << 3;
  const int d = n & 127;
  const int ig = i0 + (n >> 7);
  const int wsel = (d + 1 < 128) ? d + 1 : 127;   // d==127 pad (masked in B2)
  bf16x8 gv = *(const bf16x8*)(gw0b + wsel * 1024 + j);
  bf16x8 dv = *(const bf16x8*)(d0b + (size_t)ig * 1024 + j);
  bf16x8 v;
#pragma unroll
  for (int e = 0; e < 8; ++e) v[e] = (bf16)((float)gv[e] * (float)dv[e]);
  *(bf16x8*)(G0 + (size_t)n * 1024 + j) = v;
}

__global__ __launch_bounds__(256) void kt_gdot(const bf16* e1b, const float* bdw,
                                               const float* bdb, float* gf, float* gout) {
  const int i = blockIdx.x * 4 + (threadIdx.x >> 6);
  const int lane = threadIdx.x & 63;
  float s = 0.0f;
  for (int k = lane; k < 448; k += 64) s += (float)e1b[(size_t)i * 512 + k] * bdw[k];
#pragma unroll
  for (int off = 32; off > 0; off >>= 1) s += __shfl_down(s, off, 64);
  if (lane == 0) {
    const float v = s + bdb[0];
    gf[i] = v;
    gout[i] = v;
  }
}

__global__ __launch_bounds__(256) void kt_fin(const float* gf, const float* tr,
                                              const float* pp, float* dp) {
  const int i = blockIdx.x * 256 + threadIdx.x;
  if (i < 1024) dp[i] = gf[i] - pp[i] * tr[i];
}

extern "C" void kernel_launch(void* const* d_in, const int* in_sizes, int n_in,
                              void* d_out, int out_size, void* d_ws, size_t ws_size,
                              hipStream_t stream) {
  const float* pt  = (const float*)d_in[0];
  const float* x   = (const float*)d_in[1];
  const float* pp  = (const float*)d_in[3];
  const float* gw0 = (const float*)d_in[4];
  const float* gb0 = (const float*)d_in[5];
  const float* gw1 = (const float*)d_in[6];
  const float* gb1 = (const float*)d_in[7];
  const float* gw2 = (const float*)d_in[8];
  const float* gb2 = (const float*)d_in[9];
  const float* gdw = (const float*)d_in[10];
  const float* gdb = (const float*)d_in[11];
  const float* bw0 = (const float*)d_in[12];
  const float* bb0 = (const float*)d_in[13];
  const float* bw1 = (const float*)d_in[14];
  const float* bb1 = (const float*)d_in[15];
  const float* bdw = (const float*)d_in[16];
  const float* bdb = (const float*)d_in[17];
  float* out = (float*)d_out;

  char* w = (char*)d_ws;
  size_t used = 0;
  auto alloc = [&](size_t nbytes) -> void* {
    void* r = w + used;
    used += (nbytes + 255) & ~(size_t)255;
    return r;
  };
  bf16* gw0b = (bf16*)alloc((size_t)128 * 1024 * 2);
  bf16* gw0t = (bf16*)alloc((size_t)1024 * 128 * 2);
  bf16* gw1t = (bf16*)alloc((size_t)1024 * 1024 * 2);
  bf16* gw2t = (bf16*)alloc((size_t)1024 * 1024 * 2);
  bf16* gdwt = (bf16*)alloc((size_t)128 * 1024 * 2);
  bf16* bw0t = (bf16*)alloc((size_t)512 * 192 * 2);
  bf16* bw1t = (bf16*)alloc((size_t)512 * 512 * 2);
  bf16* Xg   = (bf16*)alloc((size_t)1024 * 128 * 2);
  bf16* Xb   = (bf16*)alloc((size_t)1024 * 192 * 2);
  bf16* h0b  = (bf16*)alloc((size_t)1024 * 1024 * 2);
  bf16* h1b  = (bf16*)alloc((size_t)1024 * 1024 * 2);
  bf16* h2b  = (bf16*)alloc((size_t)1024 * 1024 * 2);
  bf16* e0b  = (bf16*)alloc((size_t)1024 * 512 * 2);
  bf16* e1b  = (bf16*)alloc((size_t)1024 * 512 * 2);
  bf16* d0b  = (bf16*)alloc((size_t)1024 * 1024 * 2);
  bf16* d1b  = (bf16*)alloc((size_t)1024 * 960 * 2);
  bf16* d2b  = (bf16*)alloc((size_t)1024 * 896 * 2);
  float* gf  = (float*)alloc(1024 * 4);
  float* tr  = (float*)alloc(1024 * 4);

  const size_t perSample = (size_t)128 * 1024 * 2;     // 256 KB
  size_t avail = (ws_size > used) ? ws_size - used : 0;
  int CH = (int)(avail / (2 * perSample));
  if (CH > 192) CH = 192;   // B1 grid = 1536 = 2 full waves @ 3 blocks/CU
  if (CH < 1) CH = 1;
  bf16* G0  = (bf16*)alloc((size_t)CH * perSample);
  bf16* Upr = (bf16*)(w + used);

  hipMemsetAsync(tr, 0, 1024 * 4, stream);

  {
    PArgs a{gw0, gw1, gw2, gdw, bw0, bw1, pt, x,
            gw0b, gw0t, gw1t, gw2t, gdwt, bw0t, bw1t, Xg, Xb};
    kt_prep<<<dim3(11904), 256, 0, stream>>>(a);
  }

  {  // L0
    FArgs a{}; a.A = Xg; a.lda = 128; a.Bt = gw0t; a.ldb = 128; a.bias = gb0;
    a.C = h0b; a.ldc = 1024; a.D = d0b; a.ldd = 1024; a.K = 128; a.realN = 1024;
    kt_fwd<1><<<dim3(8, 8), 256, 0, stream>>>(a);
  }
  {  // L1
    FArgs a{}; a.A = h0b; a.lda = 1024; a.Bt = gw1t; a.ldb = 1024; a.bias = gb1;
    a.C = h1b; a.ldc = 1024; a.D = d1b; a.ldd = 960; a.K = 1024; a.realN = 960;
    kt_fwd<1><<<dim3(8, 8), 256, 0, stream>>>(a);
  }
  {  // L2
    FArgs a{}; a.A = h1b; a.lda = 1024; a.Bt = gw2t; a.ldb = 1024; a.bias = gb2;
    a.C = h2b; a.ldc = 1024; a.D = d2b; a.ldd = 896; a.K = 1024; a.realN = 896;
    kt_fwd<1><<<dim3(8, 7), 256, 0, stream>>>(a);
  }
  {  // dx_dt
    FArgs a{}; a.A = h2b; a.lda = 1024; a.Bt = gdwt; a.ldb = 1024; a.bias = gdb;
    a.outF = out; a.ldo = 128; a.K = 896; a.realN = 128;
    kt_fwd<0><<<dim3(8, 1), 256, 0, stream>>>(a);
  }
  {  // e0
    FArgs a{}; a.A = Xb; a.lda = 192; a.Bt = bw0t; a.ldb = 192; a.bias = bb0;
    a.C = e0b; a.ldc = 512; a.K = 192; a.realN = 512;
    kt_fwd<1><<<dim3(8, 4), 256, 0, stream>>>(a);
  }
  {  // e1
    FArgs a{}; a.A = e0b; a.lda = 512; a.Bt = bw1t; a.ldb = 512; a.bias = bb1;
    a.C = e1b; a.ldc = 512; a.K = 512; a.realN = 448;
    kt_fwd<1><<<dim3(8, 4), 256, 0, stream>>>(a);
  }
  kt_gdot<<<dim3(256), 256, 0, stream>>>(e1b, bdw, bdb, gf, out + 131072);

  for (int i0 = 0; i0 < 1024; i0 += CH) {
    const int ch = (1024 - i0 < CH) ? (1024 - i0) : CH;
    const int ch8 = (ch + 7) & ~7;
    kt_g0<<<dim3((ch * 16384 + 255) / 256), 256, 0, stream>>>(G0, gw0b, d0b, i0, ch);
    {  // B1: U' = D1 * (gw1^T @ G0), M pad 1024, K=1024
      TArgs a{}; a.A = gw1t; a.B = G0; a.d1b = d1b; a.Upr = Upr; a.i0 = i0;
      a.K = 1024; a.ch = ch;
      kt_tile<0><<<dim3(8 * ch8), 256, 0, stream>>>(a);
    }
    {  // B2: trace reduce of gw2^T @ U', M=896 (mt==7 exits), K=960
      TArgs a{}; a.A = gw2t; a.B = Upr; a.d2b = d2b; a.gdw = gdw; a.tr = tr;
      a.i0 = i0; a.K = 960; a.ch = ch;
      kt_tile<1><<<dim3(8 * ch8), 256, 0, stream>>>(a);
    }
  }

  kt_fin<<<dim3(4), 256, 0, stream>>>(gf, tr, pp, out + 132096);
}